// Round 4
// baseline (450.454 us; speedup 1.0000x reference)
//
#include <hip/hip_runtime.h>

typedef __bf16 v8bf __attribute__((ext_vector_type(8)));
typedef float f32x4 __attribute__((ext_vector_type(4)));

#define DEVI static __device__ __forceinline__

DEVI v8bf load8(const __bf16* p) { return *reinterpret_cast<const v8bf*>(p); }

DEVI f32x4 mfma16(v8bf a, v8bf b, f32x4 c) {
  return __builtin_amdgcn_mfma_f32_16x16x32_bf16(a, b, c, 0, 0, 0);
}

DEVI v8bf zero8() {
  v8bf z;
#pragma unroll
  for (int t = 0; t < 8; ++t) z[t] = (__bf16)0.0f;
  return z;
}

// async global -> LDS, 16 bytes per lane. LDS dest: wave-uniform base + lane*16.
DEVI void gld16(const __bf16* g, __bf16* l) {
  __builtin_amdgcn_global_load_lds(
      (const __attribute__((address_space(1))) unsigned int*)(const void*)g,
      (__attribute__((address_space(3))) unsigned int*)(void*)l, 16, 0, 0);
}

#define SCALE_Q 0.08838834764831845f  // 128^-0.5

// ------------------------------------------------------------------
__global__ void k_cast(const float* __restrict__ src, __bf16* __restrict__ dst, int n) {
  int i = blockIdx.x * 256 + threadIdx.x;
  if (i < n) dst[i] = (__bf16)src[i];
}

// zero the padded-z buffer (16B per thread)
__global__ void k_zero(float* __restrict__ p) {
  int i = blockIdx.x * 256 + threadIdx.x;
  f32x4 z = {0.f, 0.f, 0.f, 0.f};
  reinterpret_cast<f32x4*>(p)[i] = z;
}

// ------------------------------------------------------------------
// Repack conv weights: Wt[tap][o][c] = wfc[o][c][kh][kw], tap = kh*3+kw
// ------------------------------------------------------------------
__global__ void k_repack(const float* __restrict__ wfc, __bf16* __restrict__ Wt) {
  int idx = blockIdx.x * 256 + threadIdx.x;      // 9*512*512 total
  int c = idx & 511, o = (idx >> 9) & 511, tap = idx >> 18;
  Wt[idx] = (__bf16)wfc[((size_t)o * 512 + c) * 9 + tap];
}

// ------------------------------------------------------------------
// BN1 + ReLU on fp32 x, transpose (b,c,s) -> (b,s,c), bf16 out
// ------------------------------------------------------------------
__global__ void k_bn1(const float* __restrict__ x, const float* __restrict__ g,
                      const float* __restrict__ bb, const float* __restrict__ m,
                      const float* __restrict__ v, __bf16* __restrict__ y) {
  __shared__ float tile[32][33];
  const int b = blockIdx.z, c0 = blockIdx.y * 32, s0 = blockIdx.x * 32;
  const int tx = threadIdx.x, ty = threadIdx.y;   // 32 x 8
#pragma unroll
  for (int r = 0; r < 4; ++r) {
    int c = c0 + ty + r * 8;
    float inv = g[c] * rsqrtf(v[c] + 1e-5f);
    float beta = bb[c] - m[c] * inv;
    float val = x[((size_t)b * 512 + c) * 1024 + s0 + tx] * inv + beta;
    tile[ty + r * 8][tx] = fmaxf(val, 0.0f);
  }
  __syncthreads();
#pragma unroll
  for (int r = 0; r < 4; ++r) {
    int s = s0 + ty + r * 8;
    y[((size_t)b * 1024 + s) * 512 + c0 + tx] = (__bf16)tile[tx][ty + r * 8];
  }
}

// ------------------------------------------------------------------
// BN2 + ReLU on fp32 x2, transpose (b,c,s) -> padded (b,34,34,c), bf16 out
// ------------------------------------------------------------------
__global__ void k_bn2(const float* __restrict__ x2, const float* __restrict__ g,
                      const float* __restrict__ bb, const float* __restrict__ m,
                      const float* __restrict__ v, __bf16* __restrict__ zp) {
  __shared__ float tile[32][33];
  const int b = blockIdx.z, c0 = blockIdx.y * 32, s0 = blockIdx.x * 32;
  const int tx = threadIdx.x, ty = threadIdx.y;
#pragma unroll
  for (int r = 0; r < 4; ++r) {
    int c = c0 + ty + r * 8;
    float inv = g[c] * rsqrtf(v[c] + 1e-5f);
    float beta = bb[c] - m[c] * inv;
    float val = x2[((size_t)b * 512 + c) * 1024 + s0 + tx] * inv + beta;
    tile[ty + r * 8][tx] = fmaxf(val, 0.0f);
  }
  __syncthreads();
#pragma unroll
  for (int r = 0; r < 4; ++r) {
    int s = s0 + ty + r * 8;
    int hh = s >> 5, ww = s & 31;
    zp[(((size_t)b * 34 + hh + 1) * 34 + ww + 1) * 512 + c0 + tx] =
        (__bf16)tile[tx][ty + r * 8];
  }
}

// ------------------------------------------------------------------
// QKV projection (unchanged).
// ------------------------------------------------------------------
__global__ __launch_bounds__(256) void k_proj(
    const __bf16* __restrict__ wqk, const __bf16* __restrict__ wv,
    const __bf16* __restrict__ y, __bf16* __restrict__ qout,
    __bf16* __restrict__ kout, __bf16* __restrict__ vout) {
  const int b = blockIdx.z;
  const int wave = threadIdx.x >> 6, lane = threadIdx.x & 63;
  const int l15 = lane & 15, quad = lane >> 4;
  const int obase = blockIdx.x * 64 + (wave >> 1) * 32;
  const int sbase = blockIdx.y * 64 + (wave & 1) * 32;
  const __bf16* Amat = (obase < 1024) ? (wqk + (size_t)obase * 512)
                                      : (wv + (size_t)(obase - 1024) * 512);
  const __bf16* Bbase = y + (size_t)b * 1024 * 512;

  const f32x4 fz = {0.f, 0.f, 0.f, 0.f};
  f32x4 acc[2][2];
#pragma unroll
  for (int io = 0; io < 2; ++io)
#pragma unroll
    for (int jo = 0; jo < 2; ++jo) acc[io][jo] = fz;

  for (int k0 = 0; k0 < 512; k0 += 32) {
    v8bf a0 = load8(Amat + (size_t)l15 * 512 + k0 + quad * 8);
    v8bf a1 = load8(Amat + (size_t)(16 + l15) * 512 + k0 + quad * 8);
    v8bf b0 = load8(Bbase + (size_t)(sbase + l15) * 512 + k0 + quad * 8);
    v8bf b1 = load8(Bbase + (size_t)(sbase + 16 + l15) * 512 + k0 + quad * 8);
    acc[0][0] = mfma16(a0, b0, acc[0][0]);
    acc[0][1] = mfma16(a0, b1, acc[0][1]);
    acc[1][0] = mfma16(a1, b0, acc[1][0]);
    acc[1][1] = mfma16(a1, b1, acc[1][1]);
  }

#pragma unroll
  for (int io = 0; io < 2; ++io)
#pragma unroll
    for (int jo = 0; jo < 2; ++jo)
#pragma unroll
      for (int r = 0; r < 4; ++r) {
        int o = obase + io * 16 + quad * 4 + r;   // C row = quad*4+reg
        int s = sbase + jo * 16 + l15;            // C col = lane&15
        float val = acc[io][jo][r];
        if (o < 512) {
          int n = o >> 7, d = o & 127;
          qout[(((size_t)b * 4 + n) * 1024 + s) * 128 + d] = (__bf16)(val * SCALE_Q);
        } else if (o < 1024) {
          int oe = o - 512; int n = oe >> 7, d = oe & 127;
          kout[(((size_t)b * 4 + n) * 1024 + s) * 128 + d] = (__bf16)val;
        } else {
          int oe = o - 1024; int n = oe >> 7, d = oe & 127;
          vout[(((size_t)b * 4 + n) * 128 + d) * 1024 + s] = (__bf16)val;
        }
      }
}

// ------------------------------------------------------------------
// Flash attention: block = (b, head, 64 q-rows); each wave owns 16 q-rows
// exclusively -> all softmax state wave-private, ZERO barriers. Online
// softmax over 8 K-tiles of 128. K/V frags direct from global (L2-resident,
// XCD-swizzled grid). Rel-bias tables per wave via MFMA in LDS (f32).
// ------------------------------------------------------------------
__global__ __launch_bounds__(256) void k_attn(
    const __bf16* __restrict__ q, const __bf16* __restrict__ kmat,
    const __bf16* __restrict__ vt, const __bf16* __restrict__ relh,
    const __bf16* __restrict__ relw, const float* __restrict__ x,
    float* __restrict__ x2) {
  __shared__ float RW[64][65];      // rr = 0..62
  __shared__ float RH[64][37];      // t = 0..32  (rr = t + 30 - h0)
  __shared__ __bf16 P[4][16][136];  // per-wave un-normalized probs

  // XCD swizzle: co-locate one (b,n)'s 16 q-blocks on one XCD's L2
  const int Lb = blockIdx.x;               // 0..511
  const int xcd = Lb & 7, wi_ = Lb >> 3;
  const int bn = xcd * 4 + (wi_ & 3);
  const int qblk = wi_ >> 2;               // 0..15
  const int b = bn >> 2, n = bn & 3;
  const int s0 = qblk * 64;
  const int h0 = s0 >> 5;

  const int tid = threadIdx.x;
  const int wave = tid >> 6, lane = tid & 63;
  const int l15 = lane & 15, quad = lane >> 4;
  const int ihalf = wave >> 1;             // (i_local>>5) for this wave's rows
  const size_t hoff = ((size_t)(b * 4 + n)) << 17;   // *1024*128

  // --- Q A-fragments for this wave's 16 rows (q pre-scaled) ---
  v8bf aq[4];
  {
    const __bf16* qp = q + hoff + (size_t)(s0 + wave * 16 + l15) * 128;
#pragma unroll
    for (int kk = 0; kk < 4; ++kk) aq[kk] = load8(qp + kk * 32 + quad * 8);
  }

  // --- rel tables (wave-private rows) ---
#pragma unroll
  for (int nt = 0; nt < 4; ++nt) {         // RW: rr = nt*16+l15, valid < 63
    int rr = nt * 16 + l15;
    bool ok = rr < 63;
    const __bf16* bp = relw + (size_t)(ok ? rr : 0) * 128;
    f32x4 acc = {0.f, 0.f, 0.f, 0.f};
#pragma unroll
    for (int kk = 0; kk < 4; ++kk) {
      v8bf bf = load8(bp + kk * 32 + quad * 8);
      if (!ok) bf = zero8();
      acc = mfma16(aq[kk], bf, acc);
    }
#pragma unroll
    for (int r = 0; r < 4; ++r) RW[wave * 16 + quad * 4 + r][rr] = acc[r];
  }
#pragma unroll
  for (int nt = 0; nt < 3; ++nt) {         // RH: t = nt*16+l15, valid <= 32
    int t = nt * 16 + l15;
    int rr = t + 30 - h0;
    bool ok = t <= 32;
    const __bf16* bp = relh + (size_t)(ok ? rr : 0) * 128;
    f32x4 acc = {0.f, 0.f, 0.f, 0.f};
#pragma unroll
    for (int kk = 0; kk < 4; ++kk) {
      v8bf bf = load8(bp + kk * 32 + quad * 8);
      if (!ok) bf = zero8();
      acc = mfma16(aq[kk], bf, acc);
    }
    if (t < 37) {
#pragma unroll
      for (int r = 0; r < 4; ++r) RH[wave * 16 + quad * 4 + r][t] = acc[r];
    }
  }

  // --- online-softmax state (rows quad*4+r of this wave) ---
  float m[4] = {-1e30f, -1e30f, -1e30f, -1e30f};
  float l[4] = {0.f, 0.f, 0.f, 0.f};
  const f32x4 fz = {0.f, 0.f, 0.f, 0.f};
  f32x4 oacc[8];
#pragma unroll
  for (int dt = 0; dt < 8; ++dt) oacc[dt] = fz;

#pragma unroll 1
  for (int jt = 0; jt < 8; ++jt) {
    const int j0 = jt * 128;
    // S = Q K^T (16 x 128)
    f32x4 sacc[8];
#pragma unroll
    for (int nj = 0; nj < 8; ++nj) {
      const __bf16* bp = kmat + hoff + (size_t)(j0 + nj * 16 + l15) * 128;
      f32x4 a = fz;
#pragma unroll
      for (int kk = 0; kk < 4; ++kk)
        a = mfma16(aq[kk], load8(bp + kk * 32 + quad * 8), a);
      sacc[nj] = a;
    }
    // + rel bias; tile max
    float tmax[4] = {-1e30f, -1e30f, -1e30f, -1e30f};
#pragma unroll
    for (int nj = 0; nj < 8; ++nj) {
      const int wj = (nj & 1) * 16 + l15;
      const int hj = (j0 + nj * 16) >> 5;
      const int t = hj + 1 - ihalf;
#pragma unroll
      for (int r = 0; r < 4; ++r) {
        const int i = wave * 16 + quad * 4 + r;
        float val = sacc[nj][r] + RW[i][wj - (i & 31) + 31] + RH[i][t];
        sacc[nj][r] = val;
        tmax[r] = fmaxf(tmax[r], val);
      }
    }
#pragma unroll
    for (int r = 0; r < 4; ++r) {
#pragma unroll
      for (int msk = 8; msk >= 1; msk >>= 1)
        tmax[r] = fmaxf(tmax[r], __shfl_xor(tmax[r], msk));
      float mnew = fmaxf(m[r], tmax[r]);
      float alpha = __expf(m[r] - mnew);
      m[r] = mnew;
      l[r] *= alpha;
#pragma unroll
      for (int dt = 0; dt < 8; ++dt) oacc[dt][r] *= alpha;
    }
    // exp, sum, stash P (wave-private LDS)
    float rsum[4] = {0.f, 0.f, 0.f, 0.f};
#pragma unroll
    for (int nj = 0; nj < 8; ++nj)
#pragma unroll
      for (int r = 0; r < 4; ++r) {
        float p = __expf(sacc[nj][r] - m[r]);
        rsum[r] += p;
        P[wave][quad * 4 + r][nj * 16 + l15] = (__bf16)p;
      }
#pragma unroll
    for (int r = 0; r < 4; ++r) {
#pragma unroll
      for (int msk = 8; msk >= 1; msk >>= 1) rsum[r] += __shfl_xor(rsum[r], msk);
      l[r] += rsum[r];
    }
    // PV: O += P V  (A = P from LDS, B = V^T direct global)
    v8bf pf[4];
#pragma unroll
    for (int kk = 0; kk < 4; ++kk)
      pf[kk] = *reinterpret_cast<const v8bf*>(&P[wave][l15][kk * 32 + quad * 8]);
#pragma unroll
    for (int dt = 0; dt < 8; ++dt) {
      const __bf16* vp = vt + hoff + (size_t)(dt * 16 + l15) * 1024 + j0;
      f32x4 a = oacc[dt];
#pragma unroll
      for (int kk = 0; kk < 4; ++kk)
        a = mfma16(pf[kk], load8(vp + kk * 32 + quad * 8), a);
      oacc[dt] = a;
    }
  }

  // --- epilogue: x2 = O/l + x ---
#pragma unroll
  for (int r = 0; r < 4; ++r) {
    float inv = 1.0f / l[r];
    int s = s0 + wave * 16 + quad * 4 + r;
#pragma unroll
    for (int dt = 0; dt < 8; ++dt) {
      int d = dt * 16 + l15;
      size_t idx = ((size_t)(b * 4 + n) * 128 + d) * 1024 + s;
      x2[idx] = oacc[dt][r] * inv + x[idx];
    }
  }
}

// ------------------------------------------------------------------
// 3x3 conv, m97 structure: 128x128 tile, BK=32, global_load_lds width 16.
// ------------------------------------------------------------------
__global__ __launch_bounds__(256) void k_conv(
    const __bf16* __restrict__ Wt, const __bf16* __restrict__ zp,
    const float* __restrict__ bias, const float* __restrict__ x2,
    float* __restrict__ out) {
  __shared__ __bf16 As[128 * 32];
  __shared__ __bf16 Bs[128 * 32];
  const int t = threadIdx.x;
  const int wave = t >> 6, lane = t & 63;
  const int l15 = lane & 15, quad = lane >> 4;
  const int mbase = blockIdx.x * 128;   // o
  const int nbase = blockIdx.y * 128;   // (b,s) flat
  const int mh = (wave >> 1) * 64, nh = (wave & 1) * 64;

  const int row0 = t >> 2;              // [0,64)
  const int part8 = (t & 3) * 8;
  const __bf16* gA0 = Wt + (size_t)(mbase + row0) * 512 + part8;
  const __bf16* gA1 = gA0 + (size_t)64 * 512;
  const int n0 = nbase + row0;
  const int b0 = n0 >> 10, sp = n0 & 1023;
  const __bf16* gB0 =
      zp + ((size_t)(b0 * 34 + (sp >> 5) + 1) * 34 + (sp & 31) + 1) * 512 + part8;
  const __bf16* gB1 = gB0 + (size_t)2 * 34 * 512;
  __bf16* lA0 = As + (size_t)(wave * 64) * 8;
  __bf16* lA1 = As + (size_t)(256 + wave * 64) * 8;
  __bf16* lB0 = Bs + (size_t)(wave * 64) * 8;
  __bf16* lB1 = Bs + (size_t)(256 + wave * 64) * 8;

  const f32x4 fz = {0.f, 0.f, 0.f, 0.f};
  f32x4 acc[4][4];
#pragma unroll
  for (int i = 0; i < 4; ++i)
#pragma unroll
    for (int j = 0; j < 4; ++j) acc[i][j] = fz;

  for (int tap = 0; tap < 9; ++tap) {
    const int dh = tap / 3 - 1, dw = tap % 3 - 1;
    const size_t aoff = (size_t)tap * 512 * 512;
    const int boff = (dh * 34 + dw) * 512;
    for (int k0 = 0; k0 < 512; k0 += 32) {
      __syncthreads();
      gld16(gA0 + aoff + k0, lA0);
      gld16(gA1 + aoff + k0, lA1);
      gld16(gB0 + boff + k0, lB0);
      gld16(gB1 + boff + k0, lB1);
      __syncthreads();
      v8bf a[4], bfr[4];
#pragma unroll
      for (int i = 0; i < 4; ++i)
        a[i] = load8(&As[(size_t)(mh + i * 16 + l15) * 32 + quad * 8]);
#pragma unroll
      for (int j = 0; j < 4; ++j)
        bfr[j] = load8(&Bs[(size_t)(nh + j * 16 + l15) * 32 + quad * 8]);
#pragma unroll
      for (int i = 0; i < 4; ++i)
#pragma unroll
        for (int j = 0; j < 4; ++j) acc[i][j] = mfma16(a[i], bfr[j], acc[i][j]);
    }
  }

#pragma unroll
  for (int i = 0; i < 4; ++i)
#pragma unroll
    for (int j = 0; j < 4; ++j)
#pragma unroll
      for (int r = 0; r < 4; ++r) {
        int o = mbase + mh + i * 16 + quad * 4 + r;
        int nn = nbase + nh + j * 16 + l15;
        int bb2 = nn >> 10, s = nn & 1023;
        size_t idx = ((size_t)bb2 * 512 + o) * 1024 + s;
        out[idx] = acc[i][j][r] + bias[o] + x2[idx];
      }
}

// ------------------------------------------------------------------
extern "C" void kernel_launch(void* const* d_in, const int* in_sizes, int n_in,
                              void* d_out, int out_size, void* d_ws, size_t ws_size,
                              hipStream_t stream) {
  const float* x    = (const float*)d_in[0];
  const float* wqk  = (const float*)d_in[1];
  const float* wv   = (const float*)d_in[2];
  const float* relh = (const float*)d_in[3];
  const float* relw = (const float*)d_in[4];
  const float* g1   = (const float*)d_in[5];
  const float* b1   = (const float*)d_in[6];
  const float* m1   = (const float*)d_in[7];
  const float* v1   = (const float*)d_in[8];
  const float* g2   = (const float*)d_in[9];
  const float* b2   = (const float*)d_in[10];
  const float* m2   = (const float*)d_in[11];
  const float* v2   = (const float*)d_in[12];
  const float* wfc  = (const float*)d_in[13];
  const float* bfc  = (const float*)d_in[14];
  float* out = (float*)d_out;

  char* p = (char*)d_ws;
  __bf16* y    = (__bf16*)p; p += (size_t)8 * 1024 * 512 * 2;       // (b,s,c)
  __bf16* qb   = (__bf16*)p; p += (size_t)8 * 4 * 1024 * 128 * 2;   // (b,n,s,d)
  __bf16* kb   = (__bf16*)p; p += (size_t)8 * 4 * 1024 * 128 * 2;   // (b,n,s,d)
  __bf16* vb   = (__bf16*)p; p += (size_t)8 * 4 * 1024 * 128 * 2;   // (b,n,d,s)
  __bf16* Wt   = (__bf16*)p; p += (size_t)9 * 512 * 512 * 2;        // (tap,o,c)
  __bf16* wqkb = (__bf16*)p; p += (size_t)1024 * 512 * 2;
  __bf16* wvb  = (__bf16*)p; p += (size_t)512 * 512 * 2;
  __bf16* rhb  = (__bf16*)p; p += 32768;
  __bf16* rwb  = (__bf16*)p; p += 32768;
  float*  x2   = (float*)p;  p += (size_t)8 * 512 * 1024 * 4;       // (b,c,s) fp32
  __bf16* zpad = (__bf16*)p; p += (size_t)8 * 34 * 34 * 512 * 2;    // padded z

  k_cast<<<dim3((1024 * 512 + 255) / 256), dim3(256), 0, stream>>>(wqk, wqkb, 1024 * 512);
  k_cast<<<dim3((512 * 512 + 255) / 256), dim3(256), 0, stream>>>(wv, wvb, 512 * 512);
  k_cast<<<dim3((63 * 128 + 255) / 256), dim3(256), 0, stream>>>(relh, rhb, 63 * 128);
  k_cast<<<dim3((63 * 128 + 255) / 256), dim3(256), 0, stream>>>(relw, rwb, 63 * 128);
  k_repack<<<dim3(9 * 512 * 512 / 256), dim3(256), 0, stream>>>(wfc, Wt);
  k_zero<<<dim3(591872 / 256), dim3(256), 0, stream>>>((float*)zpad);
  k_bn1<<<dim3(32, 16, 8), dim3(32, 8), 0, stream>>>(x, g1, b1, m1, v1, y);
  k_proj<<<dim3(24, 16, 8), dim3(256), 0, stream>>>(wqkb, wvb, y, qb, kb, vb);
  k_attn<<<dim3(512), dim3(256), 0, stream>>>(qb, kb, vb, rhb, rwb, x, x2);
  k_bn2<<<dim3(32, 16, 8), dim3(32, 8), 0, stream>>>(x2, g2, b2, m2, v2, zpad);
  k_conv<<<dim3(4, 64, 1), dim3(256), 0, stream>>>(Wt, zpad, bfc, x2, out);
}

// Round 5
// 431.309 us; speedup vs baseline: 1.0444x; 1.0444x over previous
//
#include <hip/hip_runtime.h>

typedef __bf16 v8bf __attribute__((ext_vector_type(8)));
typedef float f32x4 __attribute__((ext_vector_type(4)));

#define DEVI static __device__ __forceinline__

DEVI v8bf load8(const __bf16* p) { return *reinterpret_cast<const v8bf*>(p); }

DEVI f32x4 mfma16(v8bf a, v8bf b, f32x4 c) {
  return __builtin_amdgcn_mfma_f32_16x16x32_bf16(a, b, c, 0, 0, 0);
}

DEVI v8bf zero8() {
  v8bf z;
#pragma unroll
  for (int t = 0; t < 8; ++t) z[t] = (__bf16)0.0f;
  return z;
}

// async global -> LDS, 16 bytes per lane. LDS dest: wave-uniform base + lane*16.
DEVI void gld16(const __bf16* g, __bf16* l) {
  __builtin_amdgcn_global_load_lds(
      (const __attribute__((address_space(1))) unsigned int*)(const void*)g,
      (__attribute__((address_space(3))) unsigned int*)(void*)l, 16, 0, 0);
}

#define SCALE_Q 0.08838834764831845f  // 128^-0.5

// ------------------------------------------------------------------
__global__ void k_cast(const float* __restrict__ src, __bf16* __restrict__ dst, int n) {
  int i = blockIdx.x * 256 + threadIdx.x;
  if (i < n) dst[i] = (__bf16)src[i];
}

// zero the padded-z buffer (16B per thread)
__global__ void k_zero(float* __restrict__ p) {
  int i = blockIdx.x * 256 + threadIdx.x;
  f32x4 z = {0.f, 0.f, 0.f, 0.f};
  reinterpret_cast<f32x4*>(p)[i] = z;
}

// ------------------------------------------------------------------
// Repack conv weights: Wt[tap][o][c] = wfc[o][c][kh][kw], tap = kh*3+kw
// ------------------------------------------------------------------
__global__ void k_repack(const float* __restrict__ wfc, __bf16* __restrict__ Wt) {
  int idx = blockIdx.x * 256 + threadIdx.x;      // 9*512*512 total
  int c = idx & 511, o = (idx >> 9) & 511, tap = idx >> 18;
  Wt[idx] = (__bf16)wfc[((size_t)o * 512 + c) * 9 + tap];
}

// ------------------------------------------------------------------
// BN1 + ReLU on fp32 x, transpose (b,c,s) -> (b,s,c), bf16 out
// ------------------------------------------------------------------
__global__ void k_bn1(const float* __restrict__ x, const float* __restrict__ g,
                      const float* __restrict__ bb, const float* __restrict__ m,
                      const float* __restrict__ v, __bf16* __restrict__ y) {
  __shared__ float tile[32][33];
  const int b = blockIdx.z, c0 = blockIdx.y * 32, s0 = blockIdx.x * 32;
  const int tx = threadIdx.x, ty = threadIdx.y;   // 32 x 8
#pragma unroll
  for (int r = 0; r < 4; ++r) {
    int c = c0 + ty + r * 8;
    float inv = g[c] * rsqrtf(v[c] + 1e-5f);
    float beta = bb[c] - m[c] * inv;
    float val = x[((size_t)b * 512 + c) * 1024 + s0 + tx] * inv + beta;
    tile[ty + r * 8][tx] = fmaxf(val, 0.0f);
  }
  __syncthreads();
#pragma unroll
  for (int r = 0; r < 4; ++r) {
    int s = s0 + ty + r * 8;
    y[((size_t)b * 1024 + s) * 512 + c0 + tx] = (__bf16)tile[tx][ty + r * 8];
  }
}

// ------------------------------------------------------------------
// BN2 + ReLU on fp32 x2, transpose (b,c,s) -> padded (b,34,34,c), bf16 out
// ------------------------------------------------------------------
__global__ void k_bn2(const float* __restrict__ x2, const float* __restrict__ g,
                      const float* __restrict__ bb, const float* __restrict__ m,
                      const float* __restrict__ v, __bf16* __restrict__ zp) {
  __shared__ float tile[32][33];
  const int b = blockIdx.z, c0 = blockIdx.y * 32, s0 = blockIdx.x * 32;
  const int tx = threadIdx.x, ty = threadIdx.y;
#pragma unroll
  for (int r = 0; r < 4; ++r) {
    int c = c0 + ty + r * 8;
    float inv = g[c] * rsqrtf(v[c] + 1e-5f);
    float beta = bb[c] - m[c] * inv;
    float val = x2[((size_t)b * 512 + c) * 1024 + s0 + tx] * inv + beta;
    tile[ty + r * 8][tx] = fmaxf(val, 0.0f);
  }
  __syncthreads();
#pragma unroll
  for (int r = 0; r < 4; ++r) {
    int s = s0 + ty + r * 8;
    int hh = s >> 5, ww = s & 31;
    zp[(((size_t)b * 34 + hh + 1) * 34 + ww + 1) * 512 + c0 + tx] =
        (__bf16)tile[tx][ty + r * 8];
  }
}

// ------------------------------------------------------------------
// QKV projection (unchanged).
// ------------------------------------------------------------------
__global__ __launch_bounds__(256) void k_proj(
    const __bf16* __restrict__ wqk, const __bf16* __restrict__ wv,
    const __bf16* __restrict__ y, __bf16* __restrict__ qout,
    __bf16* __restrict__ kout, __bf16* __restrict__ vout) {
  const int b = blockIdx.z;
  const int wave = threadIdx.x >> 6, lane = threadIdx.x & 63;
  const int l15 = lane & 15, quad = lane >> 4;
  const int obase = blockIdx.x * 64 + (wave >> 1) * 32;
  const int sbase = blockIdx.y * 64 + (wave & 1) * 32;
  const __bf16* Amat = (obase < 1024) ? (wqk + (size_t)obase * 512)
                                      : (wv + (size_t)(obase - 1024) * 512);
  const __bf16* Bbase = y + (size_t)b * 1024 * 512;

  const f32x4 fz = {0.f, 0.f, 0.f, 0.f};
  f32x4 acc[2][2];
#pragma unroll
  for (int io = 0; io < 2; ++io)
#pragma unroll
    for (int jo = 0; jo < 2; ++jo) acc[io][jo] = fz;

  for (int k0 = 0; k0 < 512; k0 += 32) {
    v8bf a0 = load8(Amat + (size_t)l15 * 512 + k0 + quad * 8);
    v8bf a1 = load8(Amat + (size_t)(16 + l15) * 512 + k0 + quad * 8);
    v8bf b0 = load8(Bbase + (size_t)(sbase + l15) * 512 + k0 + quad * 8);
    v8bf b1 = load8(Bbase + (size_t)(sbase + 16 + l15) * 512 + k0 + quad * 8);
    acc[0][0] = mfma16(a0, b0, acc[0][0]);
    acc[0][1] = mfma16(a0, b1, acc[0][1]);
    acc[1][0] = mfma16(a1, b0, acc[1][0]);
    acc[1][1] = mfma16(a1, b1, acc[1][1]);
  }

#pragma unroll
  for (int io = 0; io < 2; ++io)
#pragma unroll
    for (int jo = 0; jo < 2; ++jo)
#pragma unroll
      for (int r = 0; r < 4; ++r) {
        int o = obase + io * 16 + quad * 4 + r;   // C row = quad*4+reg
        int s = sbase + jo * 16 + l15;            // C col = lane&15
        float val = acc[io][jo][r];
        if (o < 512) {
          int n = o >> 7, d = o & 127;
          qout[(((size_t)b * 4 + n) * 1024 + s) * 128 + d] = (__bf16)(val * SCALE_Q);
        } else if (o < 1024) {
          int oe = o - 512; int n = oe >> 7, d = oe & 127;
          kout[(((size_t)b * 4 + n) * 1024 + s) * 128 + d] = (__bf16)val;
        } else {
          int oe = o - 1024; int n = oe >> 7, d = oe & 127;
          vout[(((size_t)b * 4 + n) * 128 + d) * 1024 + s] = (__bf16)val;
        }
      }
}

// ------------------------------------------------------------------
// Flash attention v3: block = (b, head, 16 q-rows) x 4 waves; wave w owns
// keys [w*256, w*256+256) (K-split). Fixed softmax shift c=0 (exact; logits
// clamped at 60) -> no max pass, no rescale, no per-iter cross-lane ops.
// Pre-shifted bias tables RWs[i][wj], RHs[i][hj] (h0 uniform per block).
// Partial (l, O) merged across waves via LDS at block end.
// ------------------------------------------------------------------
__global__ __launch_bounds__(256, 4) void k_attn(
    const __bf16* __restrict__ q, const __bf16* __restrict__ kmat,
    const __bf16* __restrict__ vt, const __bf16* __restrict__ relh,
    const __bf16* __restrict__ relw, const float* __restrict__ x,
    float* __restrict__ x2) {
  __shared__ float RWs[16][33];
  __shared__ float RHs[16][33];
  __shared__ float Lp[4][16];
  // P bf16 [4][16][136] (17408 B) aliases O_ld f32 [4][16][133] (34048 B)
  __shared__ __align__(16) char buf[4 * 16 * 133 * 4];
  __bf16* P = (__bf16*)buf;
  float* O_ld = (float*)buf;

  // XCD swizzle: each (b,n) head's 64 blocks on one XCD
  const int Lb = blockIdx.x;               // 0..2047
  const int xcd = Lb & 7, t_ = Lb >> 3;
  const int bn = xcd * 4 + (t_ & 3);
  const int qblk = t_ >> 2;                // 0..63
  const int s0 = qblk * 16;
  const int h0 = s0 >> 5;                  // uniform over the 16 rows
  const int wlo = s0 & 31;                 // 0 or 16

  const int tid = threadIdx.x;
  const int wave = tid >> 6, lane = tid & 63;
  const int l15 = lane & 15, quad = lane >> 4;
  const size_t hoff = ((size_t)bn) << 17;  // *1024*128

  // Q A-fragments (rows s0..s0+15) — identical in all 4 waves
  v8bf aq[4];
  {
    const __bf16* qp = q + hoff + (size_t)(s0 + l15) * 128;
#pragma unroll
    for (int kk = 0; kk < 4; ++kk) aq[kk] = load8(qp + kk * 32 + quad * 8);
  }

  if (wave == 0) {
    // RWs[i][wj] = q_i . relw[wj - (wlo+i) + 31], via 4 col-tiles + shift-write
#pragma unroll
    for (int nt = 0; nt < 4; ++nt) {
      int rr = nt * 16 + l15;              // 0..63 (rr=63 lands out of range)
      const __bf16* bp = relw + (size_t)rr * 128;
      f32x4 acc = {0.f, 0.f, 0.f, 0.f};
#pragma unroll
      for (int kk = 0; kk < 4; ++kk)
        acc = mfma16(aq[kk], load8(bp + kk * 32 + quad * 8), acc);
#pragma unroll
      for (int r = 0; r < 4; ++r) {
        int row = quad * 4 + r;
        int wj = rr + wlo + row - 31;
        if (wj >= 0 && wj < 32) RWs[row][wj] = acc[r];
      }
    }
  } else if (wave == 1) {
    // RHs[i][hj] = q_i . relh[hj - h0 + 31]  (direct GEMM, rows 31-h0..62-h0)
#pragma unroll
    for (int nt = 0; nt < 2; ++nt) {
      int hj = nt * 16 + l15;
      const __bf16* bp = relh + (size_t)(hj - h0 + 31) * 128;
      f32x4 acc = {0.f, 0.f, 0.f, 0.f};
#pragma unroll
      for (int kk = 0; kk < 4; ++kk)
        acc = mfma16(aq[kk], load8(bp + kk * 32 + quad * 8), acc);
#pragma unroll
      for (int r = 0; r < 4; ++r) RHs[quad * 4 + r][hj] = acc[r];
    }
  }
  __syncthreads();

  const f32x4 fz = {0.f, 0.f, 0.f, 0.f};
  float lsum[4] = {0.f, 0.f, 0.f, 0.f};
  f32x4 oacc[8];
#pragma unroll
  for (int dt = 0; dt < 8; ++dt) oacc[dt] = fz;
  __bf16* Pw = P + wave * 16 * 136;

#pragma unroll 1
  for (int jt = 0; jt < 2; ++jt) {
    const int j0 = wave * 256 + jt * 128;
    // S = Q K^T (16 x 128)
    f32x4 sacc[8];
#pragma unroll
    for (int nj = 0; nj < 8; ++nj) {
      const __bf16* bp = kmat + hoff + (size_t)(j0 + nj * 16 + l15) * 128;
      f32x4 a = fz;
#pragma unroll
      for (int kk = 0; kk < 4; ++kk)
        a = mfma16(aq[kk], load8(bp + kk * 32 + quad * 8), a);
      sacc[nj] = a;
    }
    // bias + exp(c=0) + per-lane partial sums + P stash
#pragma unroll
    for (int nj = 0; nj < 8; ++nj) {
      const int wj = (nj & 1) * 16 + l15;
      const int hj = (j0 + nj * 16) >> 5;
#pragma unroll
      for (int r = 0; r < 4; ++r) {
        const int row = quad * 4 + r;
        float val = sacc[nj][r] + RWs[row][wj] + RHs[row][hj];
        float p = __expf(fminf(val, 60.0f));
        lsum[r] += p;
        Pw[row * 136 + nj * 16 + l15] = (__bf16)p;
      }
    }
    // PV: O += P V  (A = P via LDS transpose, B = V^T direct global)
    v8bf pf[4];
#pragma unroll
    for (int kk = 0; kk < 4; ++kk)
      pf[kk] = *reinterpret_cast<const v8bf*>(&Pw[l15 * 136 + kk * 32 + quad * 8]);
#pragma unroll
    for (int dt = 0; dt < 8; ++dt) {
      const __bf16* vp = vt + hoff + (size_t)(dt * 16 + l15) * 1024 + j0;
      f32x4 a = oacc[dt];
#pragma unroll
      for (int kk = 0; kk < 4; ++kk)
        a = mfma16(pf[kk], load8(vp + kk * 32 + quad * 8), a);
      oacc[dt] = a;
    }
  }

  // row-sum of l partials (one reduce, after the loop)
#pragma unroll
  for (int r = 0; r < 4; ++r)
#pragma unroll
    for (int msk = 8; msk >= 1; msk >>= 1) lsum[r] += __shfl_xor(lsum[r], msk);

  __syncthreads();  // all P reads done before O_ld overwrites the alias

  // publish partials
  if (l15 == 0) {
#pragma unroll
    for (int r = 0; r < 4; ++r) Lp[wave][quad * 4 + r] = lsum[r];
  }
#pragma unroll
  for (int dt = 0; dt < 8; ++dt)
#pragma unroll
    for (int r = 0; r < 4; ++r)
      O_ld[((size_t)wave * 16 + quad * 4 + r) * 133 + dt * 16 + l15] = oacc[dt][r];
  __syncthreads();

  // merge: wave w handles d in [w*32, w*32+32); lane row = l15
  {
    float Ltot = Lp[0][l15] + Lp[1][l15] + Lp[2][l15] + Lp[3][l15];
    float inv = 1.0f / Ltot;
    const int s = s0 + l15;
#pragma unroll
    for (int c = 0; c < 8; ++c) {
      const int d = wave * 32 + quad * 8 + c;
      float o = O_ld[(size_t)(0 * 16 + l15) * 133 + d] +
                O_ld[(size_t)(1 * 16 + l15) * 133 + d] +
                O_ld[(size_t)(2 * 16 + l15) * 133 + d] +
                O_ld[(size_t)(3 * 16 + l15) * 133 + d];
      size_t idx = ((size_t)bn * 128 + d) * 1024 + s;
      x2[idx] = o * inv + x[idx];
    }
  }
}

// ------------------------------------------------------------------
// 3x3 conv, m97 structure: 128x128 tile, BK=32, global_load_lds width 16.
// ------------------------------------------------------------------
__global__ __launch_bounds__(256) void k_conv(
    const __bf16* __restrict__ Wt, const __bf16* __restrict__ zp,
    const float* __restrict__ bias, const float* __restrict__ x2,
    float* __restrict__ out) {
  __shared__ __bf16 As[128 * 32];
  __shared__ __bf16 Bs[128 * 32];
  const int t = threadIdx.x;
  const int wave = t >> 6, lane = t & 63;
  const int l15 = lane & 15, quad = lane >> 4;
  const int mbase = blockIdx.x * 128;   // o
  const int nbase = blockIdx.y * 128;   // (b,s) flat
  const int mh = (wave >> 1) * 64, nh = (wave & 1) * 64;

  const int row0 = t >> 2;              // [0,64)
  const int part8 = (t & 3) * 8;
  const __bf16* gA0 = Wt + (size_t)(mbase + row0) * 512 + part8;
  const __bf16* gA1 = gA0 + (size_t)64 * 512;
  const int n0 = nbase + row0;
  const int b0 = n0 >> 10, sp = n0 & 1023;
  const __bf16* gB0 =
      zp + ((size_t)(b0 * 34 + (sp >> 5) + 1) * 34 + (sp & 31) + 1) * 512 + part8;
  const __bf16* gB1 = gB0 + (size_t)2 * 34 * 512;
  __bf16* lA0 = As + (size_t)(wave * 64) * 8;
  __bf16* lA1 = As + (size_t)(256 + wave * 64) * 8;
  __bf16* lB0 = Bs + (size_t)(wave * 64) * 8;
  __bf16* lB1 = Bs + (size_t)(256 + wave * 64) * 8;

  const f32x4 fz = {0.f, 0.f, 0.f, 0.f};
  f32x4 acc[4][4];
#pragma unroll
  for (int i = 0; i < 4; ++i)
#pragma unroll
    for (int j = 0; j < 4; ++j) acc[i][j] = fz;

  for (int tap = 0; tap < 9; ++tap) {
    const int dh = tap / 3 - 1, dw = tap % 3 - 1;
    const size_t aoff = (size_t)tap * 512 * 512;
    const int boff = (dh * 34 + dw) * 512;
    for (int k0 = 0; k0 < 512; k0 += 32) {
      __syncthreads();
      gld16(gA0 + aoff + k0, lA0);
      gld16(gA1 + aoff + k0, lA1);
      gld16(gB0 + boff + k0, lB0);
      gld16(gB1 + boff + k0, lB1);
      __syncthreads();
      v8bf a[4], bfr[4];
#pragma unroll
      for (int i = 0; i < 4; ++i)
        a[i] = load8(&As[(size_t)(mh + i * 16 + l15) * 32 + quad * 8]);
#pragma unroll
      for (int j = 0; j < 4; ++j)
        bfr[j] = load8(&Bs[(size_t)(nh + j * 16 + l15) * 32 + quad * 8]);
#pragma unroll
      for (int i = 0; i < 4; ++i)
#pragma unroll
        for (int j = 0; j < 4; ++j) acc[i][j] = mfma16(a[i], bfr[j], acc[i][j]);
    }
  }

#pragma unroll
  for (int i = 0; i < 4; ++i)
#pragma unroll
    for (int j = 0; j < 4; ++j)
#pragma unroll
      for (int r = 0; r < 4; ++r) {
        int o = mbase + mh + i * 16 + quad * 4 + r;
        int nn = nbase + nh + j * 16 + l15;
        int bb2 = nn >> 10, s = nn & 1023;
        size_t idx = ((size_t)bb2 * 512 + o) * 1024 + s;
        out[idx] = acc[i][j][r] + bias[o] + x2[idx];
      }
}

// ------------------------------------------------------------------
extern "C" void kernel_launch(void* const* d_in, const int* in_sizes, int n_in,
                              void* d_out, int out_size, void* d_ws, size_t ws_size,
                              hipStream_t stream) {
  const float* x    = (const float*)d_in[0];
  const float* wqk  = (const float*)d_in[1];
  const float* wv   = (const float*)d_in[2];
  const float* relh = (const float*)d_in[3];
  const float* relw = (const float*)d_in[4];
  const float* g1   = (const float*)d_in[5];
  const float* b1   = (const float*)d_in[6];
  const float* m1   = (const float*)d_in[7];
  const float* v1   = (const float*)d_in[8];
  const float* g2   = (const float*)d_in[9];
  const float* b2   = (const float*)d_in[10];
  const float* m2   = (const float*)d_in[11];
  const float* v2   = (const float*)d_in[12];
  const float* wfc  = (const float*)d_in[13];
  const float* bfc  = (const float*)d_in[14];
  float* out = (float*)d_out;

  char* p = (char*)d_ws;
  __bf16* y    = (__bf16*)p; p += (size_t)8 * 1024 * 512 * 2;       // (b,s,c)
  __bf16* qb   = (__bf16*)p; p += (size_t)8 * 4 * 1024 * 128 * 2;   // (b,n,s,d)
  __bf16* kb   = (__bf16*)p; p += (size_t)8 * 4 * 1024 * 128 * 2;   // (b,n,s,d)
  __bf16* vb   = (__bf16*)p; p += (size_t)8 * 4 * 1024 * 128 * 2;   // (b,n,d,s)
  __bf16* Wt   = (__bf16*)p; p += (size_t)9 * 512 * 512 * 2;        // (tap,o,c)
  __bf16* wqkb = (__bf16*)p; p += (size_t)1024 * 512 * 2;
  __bf16* wvb  = (__bf16*)p; p += (size_t)512 * 512 * 2;
  __bf16* rhb  = (__bf16*)p; p += 32768;
  __bf16* rwb  = (__bf16*)p; p += 32768;
  float*  x2   = (float*)p;  p += (size_t)8 * 512 * 1024 * 4;       // (b,c,s) fp32
  __bf16* zpad = (__bf16*)p; p += (size_t)8 * 34 * 34 * 512 * 2;    // padded z

  k_cast<<<dim3((1024 * 512 + 255) / 256), dim3(256), 0, stream>>>(wqk, wqkb, 1024 * 512);
  k_cast<<<dim3((512 * 512 + 255) / 256), dim3(256), 0, stream>>>(wv, wvb, 512 * 512);
  k_cast<<<dim3((63 * 128 + 255) / 256), dim3(256), 0, stream>>>(relh, rhb, 63 * 128);
  k_cast<<<dim3((63 * 128 + 255) / 256), dim3(256), 0, stream>>>(relw, rwb, 63 * 128);
  k_repack<<<dim3(9 * 512 * 512 / 256), dim3(256), 0, stream>>>(wfc, Wt);
  k_zero<<<dim3(591872 / 256), dim3(256), 0, stream>>>((float*)zpad);
  k_bn1<<<dim3(32, 16, 8), dim3(32, 8), 0, stream>>>(x, g1, b1, m1, v1, y);
  k_proj<<<dim3(24, 16, 8), dim3(256), 0, stream>>>(wqkb, wvb, y, qb, kb, vb);
  k_attn<<<dim3(2048), dim3(256), 0, stream>>>(qb, kb, vb, rhb, rwb, x, x2);
  k_bn2<<<dim3(32, 16, 8), dim3(32, 8), 0, stream>>>(x2, g2, b2, m2, v2, zpad);
  k_conv<<<dim3(4, 64, 1), dim3(256), 0, stream>>>(Wt, zpad, bfc, x2, out);
}

// Round 6
// 342.910 us; speedup vs baseline: 1.3136x; 1.2578x over previous
//
#include <hip/hip_runtime.h>

typedef __bf16 v8bf __attribute__((ext_vector_type(8)));
typedef float f32x4 __attribute__((ext_vector_type(4)));

#define DEVI static __device__ __forceinline__

DEVI v8bf load8(const __bf16* p) { return *reinterpret_cast<const v8bf*>(p); }

DEVI f32x4 mfma16(v8bf a, v8bf b, f32x4 c) {
  return __builtin_amdgcn_mfma_f32_16x16x32_bf16(a, b, c, 0, 0, 0);
}

DEVI v8bf zero8() {
  v8bf z;
#pragma unroll
  for (int t = 0; t < 8; ++t) z[t] = (__bf16)0.0f;
  return z;
}

// async global -> LDS, 16 bytes per lane. LDS dest: wave-uniform base + lane*16.
DEVI void gld16(const __bf16* g, __bf16* l) {
  __builtin_amdgcn_global_load_lds(
      (const __attribute__((address_space(1))) unsigned int*)(const void*)g,
      (__attribute__((address_space(3))) unsigned int*)(void*)l, 16, 0, 0);
}

#define SCALE_Q 0.08838834764831845f  // 128^-0.5

// ------------------------------------------------------------------
__global__ void k_cast(const float* __restrict__ src, __bf16* __restrict__ dst, int n) {
  int i = blockIdx.x * 256 + threadIdx.x;
  if (i < n) dst[i] = (__bf16)src[i];
}

// zero the padded-z buffer (16B per thread)
__global__ void k_zero(float* __restrict__ p) {
  int i = blockIdx.x * 256 + threadIdx.x;
  f32x4 z = {0.f, 0.f, 0.f, 0.f};
  reinterpret_cast<f32x4*>(p)[i] = z;
}

// ------------------------------------------------------------------
// Repack conv weights: Wt[tap][o][c] = wfc[o][c][kh][kw], tap = kh*3+kw
// ------------------------------------------------------------------
__global__ void k_repack(const float* __restrict__ wfc, __bf16* __restrict__ Wt) {
  int idx = blockIdx.x * 256 + threadIdx.x;      // 9*512*512 total
  int c = idx & 511, o = (idx >> 9) & 511, tap = idx >> 18;
  Wt[idx] = (__bf16)wfc[((size_t)o * 512 + c) * 9 + tap];
}

// ------------------------------------------------------------------
// BN1 + ReLU on fp32 x, transpose (b,c,s) -> (b,s,c), bf16 out
// ------------------------------------------------------------------
__global__ void k_bn1(const float* __restrict__ x, const float* __restrict__ g,
                      const float* __restrict__ bb, const float* __restrict__ m,
                      const float* __restrict__ v, __bf16* __restrict__ y) {
  __shared__ float tile[32][33];
  const int b = blockIdx.z, c0 = blockIdx.y * 32, s0 = blockIdx.x * 32;
  const int tx = threadIdx.x, ty = threadIdx.y;   // 32 x 8
#pragma unroll
  for (int r = 0; r < 4; ++r) {
    int c = c0 + ty + r * 8;
    float inv = g[c] * rsqrtf(v[c] + 1e-5f);
    float beta = bb[c] - m[c] * inv;
    float val = x[((size_t)b * 512 + c) * 1024 + s0 + tx] * inv + beta;
    tile[ty + r * 8][tx] = fmaxf(val, 0.0f);
  }
  __syncthreads();
#pragma unroll
  for (int r = 0; r < 4; ++r) {
    int s = s0 + ty + r * 8;
    y[((size_t)b * 1024 + s) * 512 + c0 + tx] = (__bf16)tile[tx][ty + r * 8];
  }
}

// ------------------------------------------------------------------
// BN2 + ReLU on fp32 x2, transpose (b,c,s) -> padded (b,34,34,c), bf16 out
// ------------------------------------------------------------------
__global__ void k_bn2(const float* __restrict__ x2, const float* __restrict__ g,
                      const float* __restrict__ bb, const float* __restrict__ m,
                      const float* __restrict__ v, __bf16* __restrict__ zp) {
  __shared__ float tile[32][33];
  const int b = blockIdx.z, c0 = blockIdx.y * 32, s0 = blockIdx.x * 32;
  const int tx = threadIdx.x, ty = threadIdx.y;
#pragma unroll
  for (int r = 0; r < 4; ++r) {
    int c = c0 + ty + r * 8;
    float inv = g[c] * rsqrtf(v[c] + 1e-5f);
    float beta = bb[c] - m[c] * inv;
    float val = x2[((size_t)b * 512 + c) * 1024 + s0 + tx] * inv + beta;
    tile[ty + r * 8][tx] = fmaxf(val, 0.0f);
  }
  __syncthreads();
#pragma unroll
  for (int r = 0; r < 4; ++r) {
    int s = s0 + ty + r * 8;
    int hh = s >> 5, ww = s & 31;
    zp[(((size_t)b * 34 + hh + 1) * 34 + ww + 1) * 512 + c0 + tx] =
        (__bf16)tile[tx][ty + r * 8];
  }
}

// ------------------------------------------------------------------
// QKV projection (unchanged).
// ------------------------------------------------------------------
__global__ __launch_bounds__(256) void k_proj(
    const __bf16* __restrict__ wqk, const __bf16* __restrict__ wv,
    const __bf16* __restrict__ y, __bf16* __restrict__ qout,
    __bf16* __restrict__ kout, __bf16* __restrict__ vout) {
  const int b = blockIdx.z;
  const int wave = threadIdx.x >> 6, lane = threadIdx.x & 63;
  const int l15 = lane & 15, quad = lane >> 4;
  const int obase = blockIdx.x * 64 + (wave >> 1) * 32;
  const int sbase = blockIdx.y * 64 + (wave & 1) * 32;
  const __bf16* Amat = (obase < 1024) ? (wqk + (size_t)obase * 512)
                                      : (wv + (size_t)(obase - 1024) * 512);
  const __bf16* Bbase = y + (size_t)b * 1024 * 512;

  const f32x4 fz = {0.f, 0.f, 0.f, 0.f};
  f32x4 acc[2][2];
#pragma unroll
  for (int io = 0; io < 2; ++io)
#pragma unroll
    for (int jo = 0; jo < 2; ++jo) acc[io][jo] = fz;

  for (int k0 = 0; k0 < 512; k0 += 32) {
    v8bf a0 = load8(Amat + (size_t)l15 * 512 + k0 + quad * 8);
    v8bf a1 = load8(Amat + (size_t)(16 + l15) * 512 + k0 + quad * 8);
    v8bf b0 = load8(Bbase + (size_t)(sbase + l15) * 512 + k0 + quad * 8);
    v8bf b1 = load8(Bbase + (size_t)(sbase + 16 + l15) * 512 + k0 + quad * 8);
    acc[0][0] = mfma16(a0, b0, acc[0][0]);
    acc[0][1] = mfma16(a0, b1, acc[0][1]);
    acc[1][0] = mfma16(a1, b0, acc[1][0]);
    acc[1][1] = mfma16(a1, b1, acc[1][1]);
  }

#pragma unroll
  for (int io = 0; io < 2; ++io)
#pragma unroll
    for (int jo = 0; jo < 2; ++jo)
#pragma unroll
      for (int r = 0; r < 4; ++r) {
        int o = obase + io * 16 + quad * 4 + r;   // C row = quad*4+reg
        int s = sbase + jo * 16 + l15;            // C col = lane&15
        float val = acc[io][jo][r];
        if (o < 512) {
          int n = o >> 7, d = o & 127;
          qout[(((size_t)b * 4 + n) * 1024 + s) * 128 + d] = (__bf16)(val * SCALE_Q);
        } else if (o < 1024) {
          int oe = o - 512; int n = oe >> 7, d = oe & 127;
          kout[(((size_t)b * 4 + n) * 1024 + s) * 128 + d] = (__bf16)val;
        } else {
          int oe = o - 1024; int n = oe >> 7, d = oe & 127;
          vout[(((size_t)b * 4 + n) * 128 + d) * 1024 + s] = (__bf16)val;
        }
      }
}

// ------------------------------------------------------------------
// Flash attention v4 (m97-structured): block = (b, head, 64 q-rows),
// 4 waves each owning 16 rows exclusively (no merge). 16 K-tiles of 64:
// stage K (4x 64x32 chunks) + V^T (2x 128x32 chunks) via global_load_lds
// width=16, 2-barrier K-loop, all MFMA operands from LDS ds_read_b128.
// Fixed softmax shift c=0 (exact; clamp 60). Per-wave bias tables.
// ------------------------------------------------------------------
__global__ __launch_bounds__(256, 2) void k_attn(
    const __bf16* __restrict__ q, const __bf16* __restrict__ kmat,
    const __bf16* __restrict__ vt, const __bf16* __restrict__ relh,
    const __bf16* __restrict__ relw, const float* __restrict__ x,
    float* __restrict__ x2) {
  __shared__ __bf16 Ks[4 * 64 * 32];    // [kk][key_row][32 d]   16 KB
  __shared__ __bf16 Vs[2 * 128 * 32];   // [kk2][d_row][32 s]    16 KB
  __shared__ __bf16 P[4 * 16 * 72];     // per-wave probs, pad 72   9 KB
  __shared__ float RWs[64][33];         // per-row w-bias table   8.4 KB
  __shared__ float RHs[64][33];         // per-row h-bias table   8.4 KB

  // XCD swizzle: one head's 16 q-blocks on one XCD
  const int Lb = blockIdx.x;             // 0..511
  const int xcd = Lb & 7, local = Lb >> 3;
  const int bn = xcd * 4 + (local & 3);
  const int qblk = local >> 2;           // 0..15
  const int s0 = qblk * 64;

  const int t = threadIdx.x;
  const int wave = t >> 6, lane = t & 63;
  const int l15 = lane & 15, quad = lane >> 4;
  const size_t hoff = ((size_t)bn) << 17;    // *1024*128
  const int s0w = s0 + wave * 16;            // this wave's first q-row
  const int wlo = (wave & 1) * 16;           // s0w & 31
  const int h0w = s0w >> 5;                  // uniform for the wave's 16 rows

  // --- Q A-fragments (m = l15) ---
  v8bf aq[4];
  {
    const __bf16* qp = q + hoff + (size_t)(s0w + l15) * 128;
#pragma unroll
    for (int kk = 0; kk < 4; ++kk) aq[kk] = load8(qp + kk * 32 + quad * 8);
  }

  // --- per-wave bias tables (wave-private rows; no barrier needed) ---
#pragma unroll
  for (int nt = 0; nt < 4; ++nt) {       // RWs via shift-write, rr = nt*16+l15
    int rr = nt * 16 + l15;
    const __bf16* bp = relw + (size_t)rr * 128;   // rr=63 garbage, write-guarded
    f32x4 acc = {0.f, 0.f, 0.f, 0.f};
#pragma unroll
    for (int kk = 0; kk < 4; ++kk)
      acc = mfma16(aq[kk], load8(bp + kk * 32 + quad * 8), acc);
#pragma unroll
    for (int r = 0; r < 4; ++r) {
      int row = quad * 4 + r;
      int wj = rr + wlo + row - 31;
      if (wj >= 0 && wj < 32) RWs[wave * 16 + row][wj] = acc[r];
    }
  }
#pragma unroll
  for (int nt = 0; nt < 2; ++nt) {       // RHs direct: hj = nt*16+l15
    int hj = nt * 16 + l15;
    const __bf16* bp = relh + (size_t)(hj - h0w + 31) * 128;
    f32x4 acc = {0.f, 0.f, 0.f, 0.f};
#pragma unroll
    for (int kk = 0; kk < 4; ++kk)
      acc = mfma16(aq[kk], load8(bp + kk * 32 + quad * 8), acc);
#pragma unroll
    for (int r = 0; r < 4; ++r) RHs[wave * 16 + quad * 4 + r][hj] = acc[r];
  }

  // staging addresses (lane-personal global, wave-uniform LDS base)
  const int row0 = t >> 2, part8 = (t & 3) * 8;
  const __bf16* kg = kmat + hoff + (size_t)row0 * 128 + part8;
  const __bf16* vg = vt + hoff + (size_t)row0 * 1024 + part8;
  __bf16* ksw = Ks + wave * 512;
  __bf16* vsw = Vs + wave * 512;

  const f32x4 fz = {0.f, 0.f, 0.f, 0.f};
  float lsum[4] = {0.f, 0.f, 0.f, 0.f};
  f32x4 oacc[8];
#pragma unroll
  for (int dt = 0; dt < 8; ++dt) oacc[dt] = fz;
  __bf16* Pw = P + wave * 16 * 72;

#pragma unroll 1
  for (int iter = 0; iter < 16; ++iter) {
    const int j0 = iter * 64;
    __syncthreads();   // previous iteration's LDS reads done
#pragma unroll
    for (int kk = 0; kk < 4; ++kk)       // K-tile: 4 chunks of 64x32
      gld16(kg + (size_t)j0 * 128 + kk * 32, ksw + kk * 2048);
#pragma unroll
    for (int kk2 = 0; kk2 < 2; ++kk2)    // V-tile: 2 s-chunks x 2 d-halves
#pragma unroll
      for (int dh = 0; dh < 2; ++dh)
        gld16(vg + (size_t)dh * 64 * 1024 + j0 + kk2 * 32,
              vsw + kk2 * 4096 + dh * 2048);
    __syncthreads();   // staged tiles visible

    // S = Q K^T (16 x 64)
    f32x4 sacc[4];
#pragma unroll
    for (int nj = 0; nj < 4; ++nj) {
      f32x4 a = fz;
#pragma unroll
      for (int kk = 0; kk < 4; ++kk)
        a = mfma16(aq[kk],
                   load8(&Ks[kk * 2048 + (nj * 16 + l15) * 32 + quad * 8]), a);
      sacc[nj] = a;
    }
    // bias + exp(c=0) + partial l + stash P
#pragma unroll
    for (int nj = 0; nj < 4; ++nj) {
      const int wj = (nj & 1) * 16 + l15;
      const int hj = (j0 + nj * 16) >> 5;
#pragma unroll
      for (int r = 0; r < 4; ++r) {
        const int row = quad * 4 + r;
        const int gi = wave * 16 + row;
        float val = sacc[nj][r] + RWs[gi][wj] + RHs[gi][hj];
        float p = __expf(fminf(val, 60.0f));
        lsum[r] += p;
        Pw[row * 72 + nj * 16 + l15] = (__bf16)p;
      }
    }
    // PV: O += P V (A = P via LDS transpose, B = V^T from LDS)
    v8bf pf[2];
#pragma unroll
    for (int kk2 = 0; kk2 < 2; ++kk2)
      pf[kk2] = *reinterpret_cast<const v8bf*>(&Pw[l15 * 72 + kk2 * 32 + quad * 8]);
#pragma unroll
    for (int dt = 0; dt < 8; ++dt) {
      f32x4 a = oacc[dt];
#pragma unroll
      for (int kk2 = 0; kk2 < 2; ++kk2)
        a = mfma16(pf[kk2],
                   load8(&Vs[kk2 * 4096 + (dt * 16 + l15) * 32 + quad * 8]), a);
      oacc[dt] = a;
    }
  }

  // one l reduction at the very end
#pragma unroll
  for (int r = 0; r < 4; ++r)
#pragma unroll
    for (int msk = 8; msk >= 1; msk >>= 1) lsum[r] += __shfl_xor(lsum[r], msk);

  // epilogue: x2 = O/l + x
#pragma unroll
  for (int r = 0; r < 4; ++r) {
    float inv = 1.0f / lsum[r];
    int s = s0w + quad * 4 + r;
#pragma unroll
    for (int dt = 0; dt < 8; ++dt) {
      int d = dt * 16 + l15;
      size_t idx = ((size_t)bn * 128 + d) * 1024 + s;
      x2[idx] = oacc[dt][r] * inv + x[idx];
    }
  }
}

// ------------------------------------------------------------------
// 3x3 conv, m97 structure: 128x128 tile, BK=32, global_load_lds width 16.
// ------------------------------------------------------------------
__global__ __launch_bounds__(256) void k_conv(
    const __bf16* __restrict__ Wt, const __bf16* __restrict__ zp,
    const float* __restrict__ bias, const float* __restrict__ x2,
    float* __restrict__ out) {
  __shared__ __bf16 As[128 * 32];
  __shared__ __bf16 Bs[128 * 32];
  const int t = threadIdx.x;
  const int wave = t >> 6, lane = t & 63;
  const int l15 = lane & 15, quad = lane >> 4;
  const int mbase = blockIdx.x * 128;   // o
  const int nbase = blockIdx.y * 128;   // (b,s) flat
  const int mh = (wave >> 1) * 64, nh = (wave & 1) * 64;

  const int row0 = t >> 2;              // [0,64)
  const int part8 = (t & 3) * 8;
  const __bf16* gA0 = Wt + (size_t)(mbase + row0) * 512 + part8;
  const __bf16* gA1 = gA0 + (size_t)64 * 512;
  const int n0 = nbase + row0;
  const int b0 = n0 >> 10, sp = n0 & 1023;
  const __bf16* gB0 =
      zp + ((size_t)(b0 * 34 + (sp >> 5) + 1) * 34 + (sp & 31) + 1) * 512 + part8;
  const __bf16* gB1 = gB0 + (size_t)2 * 34 * 512;
  __bf16* lA0 = As + (size_t)(wave * 64) * 8;
  __bf16* lA1 = As + (size_t)(256 + wave * 64) * 8;
  __bf16* lB0 = Bs + (size_t)(wave * 64) * 8;
  __bf16* lB1 = Bs + (size_t)(256 + wave * 64) * 8;

  const f32x4 fz = {0.f, 0.f, 0.f, 0.f};
  f32x4 acc[4][4];
#pragma unroll
  for (int i = 0; i < 4; ++i)
#pragma unroll
    for (int j = 0; j < 4; ++j) acc[i][j] = fz;

  for (int tap = 0; tap < 9; ++tap) {
    const int dh = tap / 3 - 1, dw = tap % 3 - 1;
    const size_t aoff = (size_t)tap * 512 * 512;
    const int boff = (dh * 34 + dw) * 512;
    for (int k0 = 0; k0 < 512; k0 += 32) {
      __syncthreads();
      gld16(gA0 + aoff + k0, lA0);
      gld16(gA1 + aoff + k0, lA1);
      gld16(gB0 + boff + k0, lB0);
      gld16(gB1 + boff + k0, lB1);
      __syncthreads();
      v8bf a[4], bfr[4];
#pragma unroll
      for (int i = 0; i < 4; ++i)
        a[i] = load8(&As[(size_t)(mh + i * 16 + l15) * 32 + quad * 8]);
#pragma unroll
      for (int j = 0; j < 4; ++j)
        bfr[j] = load8(&Bs[(size_t)(nh + j * 16 + l15) * 32 + quad * 8]);
#pragma unroll
      for (int i = 0; i < 4; ++i)
#pragma unroll
        for (int j = 0; j < 4; ++j) acc[i][j] = mfma16(a[i], bfr[j], acc[i][j]);
    }
  }

#pragma unroll
  for (int i = 0; i < 4; ++i)
#pragma unroll
    for (int j = 0; j < 4; ++j)
#pragma unroll
      for (int r = 0; r < 4; ++r) {
        int o = mbase + mh + i * 16 + quad * 4 + r;
        int nn = nbase + nh + j * 16 + l15;
        int bb2 = nn >> 10, s = nn & 1023;
        size_t idx = ((size_t)bb2 * 512 + o) * 1024 + s;
        out[idx] = acc[i][j][r] + bias[o] + x2[idx];
      }
}

// ------------------------------------------------------------------
extern "C" void kernel_launch(void* const* d_in, const int* in_sizes, int n_in,
                              void* d_out, int out_size, void* d_ws, size_t ws_size,
                              hipStream_t stream) {
  const float* x    = (const float*)d_in[0];
  const float* wqk  = (const float*)d_in[1];
  const float* wv   = (const float*)d_in[2];
  const float* relh = (const float*)d_in[3];
  const float* relw = (const float*)d_in[4];
  const float* g1   = (const float*)d_in[5];
  const float* b1   = (const float*)d_in[6];
  const float* m1   = (const float*)d_in[7];
  const float* v1   = (const float*)d_in[8];
  const float* g2   = (const float*)d_in[9];
  const float* b2   = (const float*)d_in[10];
  const float* m2   = (const float*)d_in[11];
  const float* v2   = (const float*)d_in[12];
  const float* wfc  = (const float*)d_in[13];
  const float* bfc  = (const float*)d_in[14];
  float* out = (float*)d_out;

  char* p = (char*)d_ws;
  __bf16* y    = (__bf16*)p; p += (size_t)8 * 1024 * 512 * 2;       // (b,s,c)
  __bf16* qb   = (__bf16*)p; p += (size_t)8 * 4 * 1024 * 128 * 2;   // (b,n,s,d)
  __bf16* kb   = (__bf16*)p; p += (size_t)8 * 4 * 1024 * 128 * 2;   // (b,n,s,d)
  __bf16* vb   = (__bf16*)p; p += (size_t)8 * 4 * 1024 * 128 * 2;   // (b,n,d,s)
  __bf16* Wt   = (__bf16*)p; p += (size_t)9 * 512 * 512 * 2;        // (tap,o,c)
  __bf16* wqkb = (__bf16*)p; p += (size_t)1024 * 512 * 2;
  __bf16* wvb  = (__bf16*)p; p += (size_t)512 * 512 * 2;
  __bf16* rhb  = (__bf16*)p; p += 32768;
  __bf16* rwb  = (__bf16*)p; p += 32768;
  float*  x2   = (float*)p;  p += (size_t)8 * 512 * 1024 * 4;       // (b,c,s) fp32
  __bf16* zpad = (__bf16*)p; p += (size_t)8 * 34 * 34 * 512 * 2;    // padded z

  k_cast<<<dim3((1024 * 512 + 255) / 256), dim3(256), 0, stream>>>(wqk, wqkb, 1024 * 512);
  k_cast<<<dim3((512 * 512 + 255) / 256), dim3(256), 0, stream>>>(wv, wvb, 512 * 512);
  k_cast<<<dim3((63 * 128 + 255) / 256), dim3(256), 0, stream>>>(relh, rhb, 63 * 128);
  k_cast<<<dim3((63 * 128 + 255) / 256), dim3(256), 0, stream>>>(relw, rwb, 63 * 128);
  k_repack<<<dim3(9 * 512 * 512 / 256), dim3(256), 0, stream>>>(wfc, Wt);
  k_zero<<<dim3(591872 / 256), dim3(256), 0, stream>>>((float*)zpad);
  k_bn1<<<dim3(32, 16, 8), dim3(32, 8), 0, stream>>>(x, g1, b1, m1, v1, y);
  k_proj<<<dim3(24, 16, 8), dim3(256), 0, stream>>>(wqkb, wvb, y, qb, kb, vb);
  k_attn<<<dim3(512), dim3(256), 0, stream>>>(qb, kb, vb, rhb, rwb, x, x2);
  k_bn2<<<dim3(32, 16, 8), dim3(32, 8), 0, stream>>>(x2, g2, b2, m2, v2, zpad);
  k_conv<<<dim3(4, 64, 1), dim3(256), 0, stream>>>(Wt, zpad, bfc, x2, out);
}

// Round 7
// 283.221 us; speedup vs baseline: 1.5905x; 1.2108x over previous
//
#include <hip/hip_runtime.h>

typedef __bf16 v8bf __attribute__((ext_vector_type(8)));
typedef float f32x4 __attribute__((ext_vector_type(4)));

#define DEVI static __device__ __forceinline__

DEVI v8bf load8(const __bf16* p) { return *reinterpret_cast<const v8bf*>(p); }

DEVI f32x4 mfma16(v8bf a, v8bf b, f32x4 c) {
  return __builtin_amdgcn_mfma_f32_16x16x32_bf16(a, b, c, 0, 0, 0);
}

// async global -> LDS, 16 bytes per lane. LDS dest: wave-uniform base + lane*16.
DEVI void gld16(const __bf16* g, __bf16* l) {
  __builtin_amdgcn_global_load_lds(
      (const __attribute__((address_space(1))) unsigned int*)(const void*)g,
      (__attribute__((address_space(3))) unsigned int*)(void*)l, 16, 0, 0);
}

#define SCALE_Q 0.08838834764831845f  // 128^-0.5

// ------------------------------------------------------------------
__global__ void k_cast(const float* __restrict__ src, __bf16* __restrict__ dst, int n) {
  int i = blockIdx.x * 256 + threadIdx.x;
  if (i < n) dst[i] = (__bf16)src[i];
}

// zero the padded-z buffer (16B per thread)
__global__ void k_zero(float* __restrict__ p) {
  int i = blockIdx.x * 256 + threadIdx.x;
  f32x4 z = {0.f, 0.f, 0.f, 0.f};
  reinterpret_cast<f32x4*>(p)[i] = z;
}

// ------------------------------------------------------------------
// Repack conv weights: Wt[tap][o][c] = wfc[o][c][kh][kw].
// Thread per (o,c): 9 contiguous fp32 reads, coalesced bf16 writes per tap.
// ------------------------------------------------------------------
__global__ void k_repack(const float* __restrict__ wfc, __bf16* __restrict__ Wt) {
  int idx = blockIdx.x * 256 + threadIdx.x;      // 512*512 = (o,c) pairs
  const float* src = wfc + (size_t)idx * 9;
#pragma unroll
  for (int tap = 0; tap < 9; ++tap)
    Wt[(size_t)tap * 262144 + idx] = (__bf16)src[tap];
}

// ------------------------------------------------------------------
// BN1 + ReLU on fp32 x, transpose (b,c,s) -> (b,s,c), bf16 out
// ------------------------------------------------------------------
__global__ void k_bn1(const float* __restrict__ x, const float* __restrict__ g,
                      const float* __restrict__ bb, const float* __restrict__ m,
                      const float* __restrict__ v, __bf16* __restrict__ y) {
  __shared__ float tile[32][33];
  const int b = blockIdx.z, c0 = blockIdx.y * 32, s0 = blockIdx.x * 32;
  const int tx = threadIdx.x, ty = threadIdx.y;   // 32 x 8
#pragma unroll
  for (int r = 0; r < 4; ++r) {
    int c = c0 + ty + r * 8;
    float inv = g[c] * rsqrtf(v[c] + 1e-5f);
    float beta = bb[c] - m[c] * inv;
    float val = x[((size_t)b * 512 + c) * 1024 + s0 + tx] * inv + beta;
    tile[ty + r * 8][tx] = fmaxf(val, 0.0f);
  }
  __syncthreads();
#pragma unroll
  for (int r = 0; r < 4; ++r) {
    int s = s0 + ty + r * 8;
    y[((size_t)b * 1024 + s) * 512 + c0 + tx] = (__bf16)tile[tx][ty + r * 8];
  }
}

// ------------------------------------------------------------------
// BN2 + ReLU on fp32 x2, transpose (b,c,s) -> padded (b,34,34,c), bf16 out
// ------------------------------------------------------------------
__global__ void k_bn2(const float* __restrict__ x2, const float* __restrict__ g,
                      const float* __restrict__ bb, const float* __restrict__ m,
                      const float* __restrict__ v, __bf16* __restrict__ zp) {
  __shared__ float tile[32][33];
  const int b = blockIdx.z, c0 = blockIdx.y * 32, s0 = blockIdx.x * 32;
  const int tx = threadIdx.x, ty = threadIdx.y;
#pragma unroll
  for (int r = 0; r < 4; ++r) {
    int c = c0 + ty + r * 8;
    float inv = g[c] * rsqrtf(v[c] + 1e-5f);
    float beta = bb[c] - m[c] * inv;
    float val = x2[((size_t)b * 512 + c) * 1024 + s0 + tx] * inv + beta;
    tile[ty + r * 8][tx] = fmaxf(val, 0.0f);
  }
  __syncthreads();
#pragma unroll
  for (int r = 0; r < 4; ++r) {
    int s = s0 + ty + r * 8;
    int hh = s >> 5, ww = s & 31;
    zp[(((size_t)b * 34 + hh + 1) * 34 + ww + 1) * 512 + c0 + tx] =
        (__bf16)tile[tx][ty + r * 8];
  }
}

// ------------------------------------------------------------------
// QKV projection, m97 structure: 128x128 tile, BK=32, global_load_lds.
// A = wall [1536][512] (wqk ; wv contiguous), B = y (b*1024+s, c).
// Epilogue scatters to q (scaled, b,n,s,d), k (b,n,s,d), v (b,n,d,s).
// ------------------------------------------------------------------
__global__ __launch_bounds__(256) void k_proj(
    const __bf16* __restrict__ wall, const __bf16* __restrict__ y,
    __bf16* __restrict__ qout, __bf16* __restrict__ kout,
    __bf16* __restrict__ vout) {
  __shared__ __bf16 As[128 * 32];
  __shared__ __bf16 Bs[128 * 32];
  const int t = threadIdx.x;
  const int wave = t >> 6, lane = t & 63;
  const int l15 = lane & 15, quad = lane >> 4;
  const int mbase = blockIdx.x * 128;   // o in [0,1536)
  const int nbase = blockIdx.y * 128;   // flat (b,s)
  const int mh = (wave >> 1) * 64, nh = (wave & 1) * 64;

  const int row0 = t >> 2, part8 = (t & 3) * 8;
  const __bf16* gA0 = wall + (size_t)(mbase + row0) * 512 + part8;
  const __bf16* gA1 = gA0 + (size_t)64 * 512;
  const __bf16* gB0 = y + (size_t)(nbase + row0) * 512 + part8;
  const __bf16* gB1 = gB0 + (size_t)64 * 512;
  __bf16* lA0 = As + (size_t)(wave * 64) * 8;
  __bf16* lA1 = As + (size_t)(256 + wave * 64) * 8;
  __bf16* lB0 = Bs + (size_t)(wave * 64) * 8;
  __bf16* lB1 = Bs + (size_t)(256 + wave * 64) * 8;

  const f32x4 fz = {0.f, 0.f, 0.f, 0.f};
  f32x4 acc[4][4];
#pragma unroll
  for (int i = 0; i < 4; ++i)
#pragma unroll
    for (int j = 0; j < 4; ++j) acc[i][j] = fz;

  for (int k0 = 0; k0 < 512; k0 += 32) {
    __syncthreads();
    gld16(gA0 + k0, lA0);
    gld16(gA1 + k0, lA1);
    gld16(gB0 + k0, lB0);
    gld16(gB1 + k0, lB1);
    __syncthreads();
    v8bf a[4], bfr[4];
#pragma unroll
    for (int i = 0; i < 4; ++i)
      a[i] = load8(&As[(size_t)(mh + i * 16 + l15) * 32 + quad * 8]);
#pragma unroll
    for (int j = 0; j < 4; ++j)
      bfr[j] = load8(&Bs[(size_t)(nh + j * 16 + l15) * 32 + quad * 8]);
#pragma unroll
    for (int i = 0; i < 4; ++i)
#pragma unroll
      for (int j = 0; j < 4; ++j) acc[i][j] = mfma16(a[i], bfr[j], acc[i][j]);
  }

#pragma unroll
  for (int i = 0; i < 4; ++i)
#pragma unroll
    for (int j = 0; j < 4; ++j)
#pragma unroll
      for (int r = 0; r < 4; ++r) {
        int o = mbase + mh + i * 16 + quad * 4 + r;
        int nflat = nbase + nh + j * 16 + l15;
        int b = nflat >> 10, s = nflat & 1023;
        float val = acc[i][j][r];
        if (o < 512) {
          int n = o >> 7, d = o & 127;
          qout[(((size_t)b * 4 + n) * 1024 + s) * 128 + d] = (__bf16)(val * SCALE_Q);
        } else if (o < 1024) {
          int oe = o - 512; int n = oe >> 7, d = oe & 127;
          kout[(((size_t)b * 4 + n) * 1024 + s) * 128 + d] = (__bf16)val;
        } else {
          int oe = o - 1024; int n = oe >> 7, d = oe & 127;
          vout[(((size_t)b * 4 + n) * 128 + d) * 1024 + s] = (__bf16)val;
        }
      }
}

// ------------------------------------------------------------------
// Flash attention v4 (m97-structured): block = (b, head, 64 q-rows),
// 4 waves each owning 16 rows exclusively (no merge). 16 K-tiles of 64:
// stage K (4x 64x32 chunks) + V^T (2x 128x32 chunks) via global_load_lds
// width=16, 2-barrier K-loop, all MFMA operands from LDS ds_read_b128.
// Fixed softmax shift c=0 (exact; clamp 60). Per-wave bias tables.
// ------------------------------------------------------------------
__global__ __launch_bounds__(256, 2) void k_attn(
    const __bf16* __restrict__ q, const __bf16* __restrict__ kmat,
    const __bf16* __restrict__ vt, const __bf16* __restrict__ relh,
    const __bf16* __restrict__ relw, const float* __restrict__ x,
    float* __restrict__ x2) {
  __shared__ __bf16 Ks[4 * 64 * 32];    // [kk][key_row][32 d]   16 KB
  __shared__ __bf16 Vs[2 * 128 * 32];   // [kk2][d_row][32 s]    16 KB
  __shared__ __bf16 P[4 * 16 * 72];     // per-wave probs, pad 72   9 KB
  __shared__ float RWs[64][33];         // per-row w-bias table   8.4 KB
  __shared__ float RHs[64][33];         // per-row h-bias table   8.4 KB

  // XCD swizzle: one head's 16 q-blocks on one XCD
  const int Lb = blockIdx.x;             // 0..511
  const int xcd = Lb & 7, local = Lb >> 3;
  const int bn = xcd * 4 + (local & 3);
  const int qblk = local >> 2;           // 0..15
  const int s0 = qblk * 64;

  const int t = threadIdx.x;
  const int wave = t >> 6, lane = t & 63;
  const int l15 = lane & 15, quad = lane >> 4;
  const size_t hoff = ((size_t)bn) << 17;    // *1024*128
  const int s0w = s0 + wave * 16;            // this wave's first q-row
  const int wlo = (wave & 1) * 16;           // s0w & 31
  const int h0w = s0w >> 5;                  // uniform for the wave's 16 rows

  // --- Q A-fragments (m = l15) ---
  v8bf aq[4];
  {
    const __bf16* qp = q + hoff + (size_t)(s0w + l15) * 128;
#pragma unroll
    for (int kk = 0; kk < 4; ++kk) aq[kk] = load8(qp + kk * 32 + quad * 8);
  }

  // --- per-wave bias tables (wave-private rows; no barrier needed) ---
#pragma unroll
  for (int nt = 0; nt < 4; ++nt) {       // RWs via shift-write, rr = nt*16+l15
    int rr = nt * 16 + l15;
    const __bf16* bp = relw + (size_t)rr * 128;   // rr=63 garbage, write-guarded
    f32x4 acc = {0.f, 0.f, 0.f, 0.f};
#pragma unroll
    for (int kk = 0; kk < 4; ++kk)
      acc = mfma16(aq[kk], load8(bp + kk * 32 + quad * 8), acc);
#pragma unroll
    for (int r = 0; r < 4; ++r) {
      int row = quad * 4 + r;
      int wj = rr + wlo + row - 31;
      if (wj >= 0 && wj < 32) RWs[wave * 16 + row][wj] = acc[r];
    }
  }
#pragma unroll
  for (int nt = 0; nt < 2; ++nt) {       // RHs direct: hj = nt*16+l15
    int hj = nt * 16 + l15;
    const __bf16* bp = relh + (size_t)(hj - h0w + 31) * 128;
    f32x4 acc = {0.f, 0.f, 0.f, 0.f};
#pragma unroll
    for (int kk = 0; kk < 4; ++kk)
      acc = mfma16(aq[kk], load8(bp + kk * 32 + quad * 8), acc);
#pragma unroll
    for (int r = 0; r < 4; ++r) RHs[wave * 16 + quad * 4 + r][hj] = acc[r];
  }

  // staging addresses (lane-personal global, wave-uniform LDS base)
  const int row0 = t >> 2, part8 = (t & 3) * 8;
  const __bf16* kg = kmat + hoff + (size_t)row0 * 128 + part8;
  const __bf16* vg = vt + hoff + (size_t)row0 * 1024 + part8;
  __bf16* ksw = Ks + wave * 512;
  __bf16* vsw = Vs + wave * 512;

  const f32x4 fz = {0.f, 0.f, 0.f, 0.f};
  float lsum[4] = {0.f, 0.f, 0.f, 0.f};
  f32x4 oacc[8];
#pragma unroll
  for (int dt = 0; dt < 8; ++dt) oacc[dt] = fz;
  __bf16* Pw = P + wave * 16 * 72;

#pragma unroll 1
  for (int iter = 0; iter < 16; ++iter) {
    const int j0 = iter * 64;
    __syncthreads();   // previous iteration's LDS reads done
#pragma unroll
    for (int kk = 0; kk < 4; ++kk)       // K-tile: 4 chunks of 64x32
      gld16(kg + (size_t)j0 * 128 + kk * 32, ksw + kk * 2048);
#pragma unroll
    for (int kk2 = 0; kk2 < 2; ++kk2)    // V-tile: 2 s-chunks x 2 d-halves
#pragma unroll
      for (int dh = 0; dh < 2; ++dh)
        gld16(vg + (size_t)dh * 64 * 1024 + j0 + kk2 * 32,
              vsw + kk2 * 4096 + dh * 2048);
    __syncthreads();   // staged tiles visible

    // S = Q K^T (16 x 64)
    f32x4 sacc[4];
#pragma unroll
    for (int nj = 0; nj < 4; ++nj) {
      f32x4 a = fz;
#pragma unroll
      for (int kk = 0; kk < 4; ++kk)
        a = mfma16(aq[kk],
                   load8(&Ks[kk * 2048 + (nj * 16 + l15) * 32 + quad * 8]), a);
      sacc[nj] = a;
    }
    // bias + exp(c=0) + partial l + stash P
#pragma unroll
    for (int nj = 0; nj < 4; ++nj) {
      const int wj = (nj & 1) * 16 + l15;
      const int hj = (j0 + nj * 16) >> 5;
#pragma unroll
      for (int r = 0; r < 4; ++r) {
        const int row = quad * 4 + r;
        const int gi = wave * 16 + row;
        float val = sacc[nj][r] + RWs[gi][wj] + RHs[gi][hj];
        float p = __expf(fminf(val, 60.0f));
        lsum[r] += p;
        Pw[row * 72 + nj * 16 + l15] = (__bf16)p;
      }
    }
    // PV: O += P V (A = P via LDS transpose, B = V^T from LDS)
    v8bf pf[2];
#pragma unroll
    for (int kk2 = 0; kk2 < 2; ++kk2)
      pf[kk2] = *reinterpret_cast<const v8bf*>(&Pw[l15 * 72 + kk2 * 32 + quad * 8]);
#pragma unroll
    for (int dt = 0; dt < 8; ++dt) {
      f32x4 a = oacc[dt];
#pragma unroll
      for (int kk2 = 0; kk2 < 2; ++kk2)
        a = mfma16(pf[kk2],
                   load8(&Vs[kk2 * 4096 + (dt * 16 + l15) * 32 + quad * 8]), a);
      oacc[dt] = a;
    }
  }

  // one l reduction at the very end
#pragma unroll
  for (int r = 0; r < 4; ++r)
#pragma unroll
    for (int msk = 8; msk >= 1; msk >>= 1) lsum[r] += __shfl_xor(lsum[r], msk);

  // epilogue: x2 = O/l + x
#pragma unroll
  for (int r = 0; r < 4; ++r) {
    float inv = 1.0f / lsum[r];
    int s = s0w + quad * 4 + r;
#pragma unroll
    for (int dt = 0; dt < 8; ++dt) {
      int d = dt * 16 + l15;
      size_t idx = ((size_t)bn * 128 + d) * 1024 + s;
      x2[idx] = oacc[dt][r] * inv + x[idx];
    }
  }
}

// ------------------------------------------------------------------
// 3x3 conv, m97 structure: 128x128 tile, BK=32, global_load_lds width 16.
// ------------------------------------------------------------------
__global__ __launch_bounds__(256) void k_conv(
    const __bf16* __restrict__ Wt, const __bf16* __restrict__ zp,
    const float* __restrict__ bias, const float* __restrict__ x2,
    float* __restrict__ out) {
  __shared__ __bf16 As[128 * 32];
  __shared__ __bf16 Bs[128 * 32];
  const int t = threadIdx.x;
  const int wave = t >> 6, lane = t & 63;
  const int l15 = lane & 15, quad = lane >> 4;
  const int mbase = blockIdx.x * 128;   // o
  const int nbase = blockIdx.y * 128;   // (b,s) flat
  const int mh = (wave >> 1) * 64, nh = (wave & 1) * 64;

  const int row0 = t >> 2;              // [0,64)
  const int part8 = (t & 3) * 8;
  const __bf16* gA0 = Wt + (size_t)(mbase + row0) * 512 + part8;
  const __bf16* gA1 = gA0 + (size_t)64 * 512;
  const int n0 = nbase + row0;
  const int b0 = n0 >> 10, sp = n0 & 1023;
  const __bf16* gB0 =
      zp + ((size_t)(b0 * 34 + (sp >> 5) + 1) * 34 + (sp & 31) + 1) * 512 + part8;
  const __bf16* gB1 = gB0 + (size_t)2 * 34 * 512;
  __bf16* lA0 = As + (size_t)(wave * 64) * 8;
  __bf16* lA1 = As + (size_t)(256 + wave * 64) * 8;
  __bf16* lB0 = Bs + (size_t)(wave * 64) * 8;
  __bf16* lB1 = Bs + (size_t)(256 + wave * 64) * 8;

  const f32x4 fz = {0.f, 0.f, 0.f, 0.f};
  f32x4 acc[4][4];
#pragma unroll
  for (int i = 0; i < 4; ++i)
#pragma unroll
    for (int j = 0; j < 4; ++j) acc[i][j] = fz;

  for (int tap = 0; tap < 9; ++tap) {
    const int dh = tap / 3 - 1, dw = tap % 3 - 1;
    const size_t aoff = (size_t)tap * 512 * 512;
    const int boff = (dh * 34 + dw) * 512;
    for (int k0 = 0; k0 < 512; k0 += 32) {
      __syncthreads();
      gld16(gA0 + aoff + k0, lA0);
      gld16(gA1 + aoff + k0, lA1);
      gld16(gB0 + boff + k0, lB0);
      gld16(gB1 + boff + k0, lB1);
      __syncthreads();
      v8bf a[4], bfr[4];
#pragma unroll
      for (int i = 0; i < 4; ++i)
        a[i] = load8(&As[(size_t)(mh + i * 16 + l15) * 32 + quad * 8]);
#pragma unroll
      for (int j = 0; j < 4; ++j)
        bfr[j] = load8(&Bs[(size_t)(nh + j * 16 + l15) * 32 + quad * 8]);
#pragma unroll
      for (int i = 0; i < 4; ++i)
#pragma unroll
        for (int j = 0; j < 4; ++j) acc[i][j] = mfma16(a[i], bfr[j], acc[i][j]);
    }
  }

#pragma unroll
  for (int i = 0; i < 4; ++i)
#pragma unroll
    for (int j = 0; j < 4; ++j)
#pragma unroll
      for (int r = 0; r < 4; ++r) {
        int o = mbase + mh + i * 16 + quad * 4 + r;
        int nn = nbase + nh + j * 16 + l15;
        int bb2 = nn >> 10, s = nn & 1023;
        size_t idx = ((size_t)bb2 * 512 + o) * 1024 + s;
        out[idx] = acc[i][j][r] + bias[o] + x2[idx];
      }
}

// ------------------------------------------------------------------
extern "C" void kernel_launch(void* const* d_in, const int* in_sizes, int n_in,
                              void* d_out, int out_size, void* d_ws, size_t ws_size,
                              hipStream_t stream) {
  const float* x    = (const float*)d_in[0];
  const float* wqk  = (const float*)d_in[1];
  const float* wv   = (const float*)d_in[2];
  const float* relh = (const float*)d_in[3];
  const float* relw = (const float*)d_in[4];
  const float* g1   = (const float*)d_in[5];
  const float* b1   = (const float*)d_in[6];
  const float* m1   = (const float*)d_in[7];
  const float* v1   = (const float*)d_in[8];
  const float* g2   = (const float*)d_in[9];
  const float* b2   = (const float*)d_in[10];
  const float* m2   = (const float*)d_in[11];
  const float* v2   = (const float*)d_in[12];
  const float* wfc  = (const float*)d_in[13];
  const float* bfc  = (const float*)d_in[14];
  float* out = (float*)d_out;

  char* p = (char*)d_ws;
  __bf16* y    = (__bf16*)p; p += (size_t)8 * 1024 * 512 * 2;       // (b,s,c)
  __bf16* qb   = (__bf16*)p; p += (size_t)8 * 4 * 1024 * 128 * 2;   // (b,n,s,d)
  __bf16* kb   = (__bf16*)p; p += (size_t)8 * 4 * 1024 * 128 * 2;   // (b,n,s,d)
  __bf16* vb   = (__bf16*)p; p += (size_t)8 * 4 * 1024 * 128 * 2;   // (b,n,d,s)
  __bf16* Wt   = (__bf16*)p; p += (size_t)9 * 512 * 512 * 2;        // (tap,o,c)
  __bf16* wqkb = (__bf16*)p; p += (size_t)1024 * 512 * 2;           // [wall rows 0..1023]
  __bf16* wvb  = (__bf16*)p; p += (size_t)512 * 512 * 2;            // [wall rows 1024..1535]
  __bf16* rhb  = (__bf16*)p; p += 32768;
  __bf16* rwb  = (__bf16*)p; p += 32768;
  float*  x2   = (float*)p;  p += (size_t)8 * 512 * 1024 * 4;       // (b,c,s) fp32
  __bf16* zpad = (__bf16*)p; p += (size_t)8 * 34 * 34 * 512 * 2;    // padded z

  k_cast<<<dim3((1024 * 512 + 255) / 256), dim3(256), 0, stream>>>(wqk, wqkb, 1024 * 512);
  k_cast<<<dim3((512 * 512 + 255) / 256), dim3(256), 0, stream>>>(wv, wvb, 512 * 512);
  k_cast<<<dim3((63 * 128 + 255) / 256), dim3(256), 0, stream>>>(relh, rhb, 63 * 128);
  k_cast<<<dim3((63 * 128 + 255) / 256), dim3(256), 0, stream>>>(relw, rwb, 63 * 128);
  k_repack<<<dim3(512 * 512 / 256), dim3(256), 0, stream>>>(wfc, Wt);
  k_zero<<<dim3(591872 / 256), dim3(256), 0, stream>>>((float*)zpad);
  k_bn1<<<dim3(32, 16, 8), dim3(32, 8), 0, stream>>>(x, g1, b1, m1, v1, y);
  k_proj<<<dim3(12, 64), dim3(256), 0, stream>>>(wqkb, y, qb, kb, vb);
  k_attn<<<dim3(512), dim3(256), 0, stream>>>(qb, kb, vb, rhb, rwb, x, x2);
  k_bn2<<<dim3(32, 16, 8), dim3(32, 8), 0, stream>>>(x2, g2, b2, m2, v2, zpad);
  k_conv<<<dim3(4, 64, 1), dim3(256), 0, stream>>>(Wt, zpad, bfc, x2, out);
}

// Round 8
// 269.876 us; speedup vs baseline: 1.6691x; 1.0494x over previous
//
#include <hip/hip_runtime.h>

typedef __bf16 v8bf __attribute__((ext_vector_type(8)));
typedef float f32x4 __attribute__((ext_vector_type(4)));

#define DEVI static __device__ __forceinline__

DEVI v8bf load8(const __bf16* p) { return *reinterpret_cast<const v8bf*>(p); }

DEVI f32x4 mfma16(v8bf a, v8bf b, f32x4 c) {
  return __builtin_amdgcn_mfma_f32_16x16x32_bf16(a, b, c, 0, 0, 0);
}

// async global -> LDS, 16 bytes per lane. LDS dest: wave-uniform base + lane*16.
DEVI void gld16(const __bf16* g, __bf16* l) {
  __builtin_amdgcn_global_load_lds(
      (const __attribute__((address_space(1))) unsigned int*)(const void*)g,
      (__attribute__((address_space(3))) unsigned int*)(void*)l, 16, 0, 0);
}

#define SCALE_Q 0.08838834764831845f  // 128^-0.5

// ------------------------------------------------------------------
__global__ void k_cast(const float* __restrict__ src, __bf16* __restrict__ dst, int n) {
  int i = blockIdx.x * 256 + threadIdx.x;
  if (i < n) dst[i] = (__bf16)src[i];
}

// zero the padded-z buffer (16B per thread)
__global__ void k_zero(float* __restrict__ p) {
  int i = blockIdx.x * 256 + threadIdx.x;
  f32x4 z = {0.f, 0.f, 0.f, 0.f};
  reinterpret_cast<f32x4*>(p)[i] = z;
}

// ------------------------------------------------------------------
// Repack conv weights: Wt[tap][o][c] = wfc[o][c][kh][kw].
// Thread per (o,c): 9 contiguous fp32 reads, coalesced bf16 writes per tap.
// ------------------------------------------------------------------
__global__ void k_repack(const float* __restrict__ wfc, __bf16* __restrict__ Wt) {
  int idx = blockIdx.x * 256 + threadIdx.x;      // 512*512 = (o,c) pairs
  const float* src = wfc + (size_t)idx * 9;
#pragma unroll
  for (int tap = 0; tap < 9; ++tap)
    Wt[(size_t)tap * 262144 + idx] = (__bf16)src[tap];
}

// ------------------------------------------------------------------
// BN1 + ReLU on fp32 x, transpose (b,c,s) -> (b,s,c), bf16 out
// ------------------------------------------------------------------
__global__ void k_bn1(const float* __restrict__ x, const float* __restrict__ g,
                      const float* __restrict__ bb, const float* __restrict__ m,
                      const float* __restrict__ v, __bf16* __restrict__ y) {
  __shared__ float tile[32][33];
  const int b = blockIdx.z, c0 = blockIdx.y * 32, s0 = blockIdx.x * 32;
  const int tx = threadIdx.x, ty = threadIdx.y;   // 32 x 8
#pragma unroll
  for (int r = 0; r < 4; ++r) {
    int c = c0 + ty + r * 8;
    float inv = g[c] * rsqrtf(v[c] + 1e-5f);
    float beta = bb[c] - m[c] * inv;
    float val = x[((size_t)b * 512 + c) * 1024 + s0 + tx] * inv + beta;
    tile[ty + r * 8][tx] = fmaxf(val, 0.0f);
  }
  __syncthreads();
#pragma unroll
  for (int r = 0; r < 4; ++r) {
    int s = s0 + ty + r * 8;
    y[((size_t)b * 1024 + s) * 512 + c0 + tx] = (__bf16)tile[tx][ty + r * 8];
  }
}

// ------------------------------------------------------------------
// BN2 + ReLU on fp32 x2, transpose (b,c,s) -> padded (b,34,34,c), bf16 out
// ------------------------------------------------------------------
__global__ void k_bn2(const float* __restrict__ x2, const float* __restrict__ g,
                      const float* __restrict__ bb, const float* __restrict__ m,
                      const float* __restrict__ v, __bf16* __restrict__ zp) {
  __shared__ float tile[32][33];
  const int b = blockIdx.z, c0 = blockIdx.y * 32, s0 = blockIdx.x * 32;
  const int tx = threadIdx.x, ty = threadIdx.y;
#pragma unroll
  for (int r = 0; r < 4; ++r) {
    int c = c0 + ty + r * 8;
    float inv = g[c] * rsqrtf(v[c] + 1e-5f);
    float beta = bb[c] - m[c] * inv;
    float val = x2[((size_t)b * 512 + c) * 1024 + s0 + tx] * inv + beta;
    tile[ty + r * 8][tx] = fmaxf(val, 0.0f);
  }
  __syncthreads();
#pragma unroll
  for (int r = 0; r < 4; ++r) {
    int s = s0 + ty + r * 8;
    int hh = s >> 5, ww = s & 31;
    zp[(((size_t)b * 34 + hh + 1) * 34 + ww + 1) * 512 + c0 + tx] =
        (__bf16)tile[tx][ty + r * 8];
  }
}

// ------------------------------------------------------------------
// QKV projection, m97 structure: 128x128 tile, BK=32, global_load_lds.
// A = wall [1536][512] (wqk ; wv contiguous), B = y (b*1024+s, c).
// Epilogue scatters to q (scaled, b,n,s,d), k (b,n,s,d), v (b,n,d,s).
// ------------------------------------------------------------------
__global__ __launch_bounds__(256) void k_proj(
    const __bf16* __restrict__ wall, const __bf16* __restrict__ y,
    __bf16* __restrict__ qout, __bf16* __restrict__ kout,
    __bf16* __restrict__ vout) {
  __shared__ __bf16 As[128 * 32];
  __shared__ __bf16 Bs[128 * 32];
  const int t = threadIdx.x;
  const int wave = t >> 6, lane = t & 63;
  const int l15 = lane & 15, quad = lane >> 4;
  const int mbase = blockIdx.x * 128;   // o in [0,1536)
  const int nbase = blockIdx.y * 128;   // flat (b,s)
  const int mh = (wave >> 1) * 64, nh = (wave & 1) * 64;

  const int row0 = t >> 2, part8 = (t & 3) * 8;
  const __bf16* gA0 = wall + (size_t)(mbase + row0) * 512 + part8;
  const __bf16* gA1 = gA0 + (size_t)64 * 512;
  const __bf16* gB0 = y + (size_t)(nbase + row0) * 512 + part8;
  const __bf16* gB1 = gB0 + (size_t)64 * 512;
  __bf16* lA0 = As + (size_t)(wave * 64) * 8;
  __bf16* lA1 = As + (size_t)(256 + wave * 64) * 8;
  __bf16* lB0 = Bs + (size_t)(wave * 64) * 8;
  __bf16* lB1 = Bs + (size_t)(256 + wave * 64) * 8;

  const f32x4 fz = {0.f, 0.f, 0.f, 0.f};
  f32x4 acc[4][4];
#pragma unroll
  for (int i = 0; i < 4; ++i)
#pragma unroll
    for (int j = 0; j < 4; ++j) acc[i][j] = fz;

  for (int k0 = 0; k0 < 512; k0 += 32) {
    __syncthreads();
    gld16(gA0 + k0, lA0);
    gld16(gA1 + k0, lA1);
    gld16(gB0 + k0, lB0);
    gld16(gB1 + k0, lB1);
    __syncthreads();
    v8bf a[4], bfr[4];
#pragma unroll
    for (int i = 0; i < 4; ++i)
      a[i] = load8(&As[(size_t)(mh + i * 16 + l15) * 32 + quad * 8]);
#pragma unroll
    for (int j = 0; j < 4; ++j)
      bfr[j] = load8(&Bs[(size_t)(nh + j * 16 + l15) * 32 + quad * 8]);
#pragma unroll
    for (int i = 0; i < 4; ++i)
#pragma unroll
      for (int j = 0; j < 4; ++j) acc[i][j] = mfma16(a[i], bfr[j], acc[i][j]);
  }

#pragma unroll
  for (int i = 0; i < 4; ++i)
#pragma unroll
    for (int j = 0; j < 4; ++j)
#pragma unroll
      for (int r = 0; r < 4; ++r) {
        int o = mbase + mh + i * 16 + quad * 4 + r;
        int nflat = nbase + nh + j * 16 + l15;
        int b = nflat >> 10, s = nflat & 1023;
        float val = acc[i][j][r];
        if (o < 512) {
          int n = o >> 7, d = o & 127;
          qout[(((size_t)b * 4 + n) * 1024 + s) * 128 + d] = (__bf16)(val * SCALE_Q);
        } else if (o < 1024) {
          int oe = o - 512; int n = oe >> 7, d = oe & 127;
          kout[(((size_t)b * 4 + n) * 1024 + s) * 128 + d] = (__bf16)val;
        } else {
          int oe = o - 1024; int n = oe >> 7, d = oe & 127;
          vout[(((size_t)b * 4 + n) * 128 + d) * 1024 + s] = (__bf16)val;
        }
      }
}

// ------------------------------------------------------------------
// Flash attention v4 (m97-structured): block = (b, head, 64 q-rows),
// 4 waves each owning 16 rows exclusively (no merge). 16 K-tiles of 64:
// stage K (4x 64x32 chunks) + V^T (2x 128x32 chunks) via global_load_lds
// width=16, 2-barrier K-loop, all MFMA operands from LDS ds_read_b128.
// Fixed softmax shift c=0 (exact; clamp 60). Per-wave bias tables.
// ------------------------------------------------------------------
__global__ __launch_bounds__(256, 2) void k_attn(
    const __bf16* __restrict__ q, const __bf16* __restrict__ kmat,
    const __bf16* __restrict__ vt, const __bf16* __restrict__ relh,
    const __bf16* __restrict__ relw, const float* __restrict__ x,
    float* __restrict__ x2) {
  __shared__ __bf16 Ks[4 * 64 * 32];    // [kk][key_row][32 d]   16 KB
  __shared__ __bf16 Vs[2 * 128 * 32];   // [kk2][d_row][32 s]    16 KB
  __shared__ __bf16 P[4 * 16 * 72];     // per-wave probs, pad 72   9 KB
  __shared__ float RWs[64][33];         // per-row w-bias table   8.4 KB
  __shared__ float RHs[64][33];         // per-row h-bias table   8.4 KB

  // XCD swizzle: one head's 16 q-blocks on one XCD
  const int Lb = blockIdx.x;             // 0..511
  const int xcd = Lb & 7, local = Lb >> 3;
  const int bn = xcd * 4 + (local & 3);
  const int qblk = local >> 2;           // 0..15
  const int s0 = qblk * 64;

  const int t = threadIdx.x;
  const int wave = t >> 6, lane = t & 63;
  const int l15 = lane & 15, quad = lane >> 4;
  const size_t hoff = ((size_t)bn) << 17;    // *1024*128
  const int s0w = s0 + wave * 16;            // this wave's first q-row
  const int wlo = (wave & 1) * 16;           // s0w & 31
  const int h0w = s0w >> 5;                  // uniform for the wave's 16 rows

  // --- Q A-fragments (m = l15) ---
  v8bf aq[4];
  {
    const __bf16* qp = q + hoff + (size_t)(s0w + l15) * 128;
#pragma unroll
    for (int kk = 0; kk < 4; ++kk) aq[kk] = load8(qp + kk * 32 + quad * 8);
  }

  // --- per-wave bias tables (wave-private rows; no barrier needed) ---
#pragma unroll
  for (int nt = 0; nt < 4; ++nt) {       // RWs via shift-write, rr = nt*16+l15
    int rr = nt * 16 + l15;
    const __bf16* bp = relw + (size_t)rr * 128;   // rr=63 garbage, write-guarded
    f32x4 acc = {0.f, 0.f, 0.f, 0.f};
#pragma unroll
    for (int kk = 0; kk < 4; ++kk)
      acc = mfma16(aq[kk], load8(bp + kk * 32 + quad * 8), acc);
#pragma unroll
    for (int r = 0; r < 4; ++r) {
      int row = quad * 4 + r;
      int wj = rr + wlo + row - 31;
      if (wj >= 0 && wj < 32) RWs[wave * 16 + row][wj] = acc[r];
    }
  }
#pragma unroll
  for (int nt = 0; nt < 2; ++nt) {       // RHs direct: hj = nt*16+l15
    int hj = nt * 16 + l15;
    const __bf16* bp = relh + (size_t)(hj - h0w + 31) * 128;
    f32x4 acc = {0.f, 0.f, 0.f, 0.f};
#pragma unroll
    for (int kk = 0; kk < 4; ++kk)
      acc = mfma16(aq[kk], load8(bp + kk * 32 + quad * 8), acc);
#pragma unroll
    for (int r = 0; r < 4; ++r) RHs[wave * 16 + quad * 4 + r][hj] = acc[r];
  }

  // staging addresses (lane-personal global, wave-uniform LDS base)
  const int row0 = t >> 2, part8 = (t & 3) * 8;
  const __bf16* kg = kmat + hoff + (size_t)row0 * 128 + part8;
  const __bf16* vg = vt + hoff + (size_t)row0 * 1024 + part8;
  __bf16* ksw = Ks + wave * 512;
  __bf16* vsw = Vs + wave * 512;

  const f32x4 fz = {0.f, 0.f, 0.f, 0.f};
  float lsum[4] = {0.f, 0.f, 0.f, 0.f};
  f32x4 oacc[8];
#pragma unroll
  for (int dt = 0; dt < 8; ++dt) oacc[dt] = fz;
  __bf16* Pw = P + wave * 16 * 72;

#pragma unroll 1
  for (int iter = 0; iter < 16; ++iter) {
    const int j0 = iter * 64;
    __syncthreads();   // previous iteration's LDS reads done
#pragma unroll
    for (int kk = 0; kk < 4; ++kk)       // K-tile: 4 chunks of 64x32
      gld16(kg + (size_t)j0 * 128 + kk * 32, ksw + kk * 2048);
#pragma unroll
    for (int kk2 = 0; kk2 < 2; ++kk2)    // V-tile: 2 s-chunks x 2 d-halves
#pragma unroll
      for (int dh = 0; dh < 2; ++dh)
        gld16(vg + (size_t)dh * 64 * 1024 + j0 + kk2 * 32,
              vsw + kk2 * 4096 + dh * 2048);
    __syncthreads();   // staged tiles visible

    // S = Q K^T (16 x 64)
    f32x4 sacc[4];
#pragma unroll
    for (int nj = 0; nj < 4; ++nj) {
      f32x4 a = fz;
#pragma unroll
      for (int kk = 0; kk < 4; ++kk)
        a = mfma16(aq[kk],
                   load8(&Ks[kk * 2048 + (nj * 16 + l15) * 32 + quad * 8]), a);
      sacc[nj] = a;
    }
    // bias + exp(c=0) + partial l + stash P
#pragma unroll
    for (int nj = 0; nj < 4; ++nj) {
      const int wj = (nj & 1) * 16 + l15;
      const int hj = (j0 + nj * 16) >> 5;
#pragma unroll
      for (int r = 0; r < 4; ++r) {
        const int row = quad * 4 + r;
        const int gi = wave * 16 + row;
        float val = sacc[nj][r] + RWs[gi][wj] + RHs[gi][hj];
        float p = __expf(fminf(val, 60.0f));
        lsum[r] += p;
        Pw[row * 72 + nj * 16 + l15] = (__bf16)p;
      }
    }
    // PV: O += P V (A = P via LDS transpose, B = V^T from LDS)
    v8bf pf[2];
#pragma unroll
    for (int kk2 = 0; kk2 < 2; ++kk2)
      pf[kk2] = *reinterpret_cast<const v8bf*>(&Pw[l15 * 72 + kk2 * 32 + quad * 8]);
#pragma unroll
    for (int dt = 0; dt < 8; ++dt) {
      f32x4 a = oacc[dt];
#pragma unroll
      for (int kk2 = 0; kk2 < 2; ++kk2)
        a = mfma16(pf[kk2],
                   load8(&Vs[kk2 * 4096 + (dt * 16 + l15) * 32 + quad * 8]), a);
      oacc[dt] = a;
    }
  }

  // one l reduction at the very end
#pragma unroll
  for (int r = 0; r < 4; ++r)
#pragma unroll
    for (int msk = 8; msk >= 1; msk >>= 1) lsum[r] += __shfl_xor(lsum[r], msk);

  // epilogue: x2 = O/l + x
#pragma unroll
  for (int r = 0; r < 4; ++r) {
    float inv = 1.0f / lsum[r];
    int s = s0w + quad * 4 + r;
#pragma unroll
    for (int dt = 0; dt < 8; ++dt) {
      int d = dt * 16 + l15;
      size_t idx = ((size_t)bn * 128 + d) * 1024 + s;
      x2[idx] = oacc[dt][r] * inv + x[idx];
    }
  }
}

// ------------------------------------------------------------------
// 3x3 conv, BK=128: 9 taps x 4 k-chunks = 36 iterations (vs 144 at BK=32).
// Grid is capacity-pinned at 1 block/CU, so the barrier drain is fully
// exposed; fewer/fatter drains shorten the critical path ~4x. LDS layout
// stays 4 separate 128x32 m97-chunks (64B rows) to avoid the bank-0
// pileup a flat [128][128] (256B row stride) would cause.
// ------------------------------------------------------------------
__global__ __launch_bounds__(256) void k_conv(
    const __bf16* __restrict__ Wt, const __bf16* __restrict__ zp,
    const float* __restrict__ bias, const float* __restrict__ x2,
    float* __restrict__ out) {
  __shared__ __bf16 As[4 * 128 * 32];   // 32 KB: chunk c = k-slice [c*32,c*32+32)
  __shared__ __bf16 Bs[4 * 128 * 32];   // 32 KB
  const int t = threadIdx.x;
  const int wave = t >> 6, lane = t & 63;
  const int l15 = lane & 15, quad = lane >> 4;
  const int mbase = blockIdx.x * 128;   // o
  const int nbase = blockIdx.y * 128;   // (b,s) flat
  const int mh = (wave >> 1) * 64, nh = (wave & 1) * 64;

  const int row0 = t >> 2;              // [0,64)
  const int part8 = (t & 3) * 8;
  const __bf16* gA0 = Wt + (size_t)(mbase + row0) * 512 + part8;   // rows 0..63
  const __bf16* gA1 = gA0 + (size_t)64 * 512;                     // rows 64..127
  const int n0 = nbase + row0;
  const int b0 = n0 >> 10, sp = n0 & 1023;
  const __bf16* gB0 =
      zp + ((size_t)(b0 * 34 + (sp >> 5) + 1) * 34 + (sp & 31) + 1) * 512 + part8;
  const __bf16* gB1 = gB0 + (size_t)2 * 34 * 512;   // spatial +64 -> h+2
  const int wofs = wave * 512;          // each wave stages 64 lanes x 8 elems

  const f32x4 fz = {0.f, 0.f, 0.f, 0.f};
  f32x4 acc[4][4];
#pragma unroll
  for (int i = 0; i < 4; ++i)
#pragma unroll
    for (int j = 0; j < 4; ++j) acc[i][j] = fz;

#pragma unroll 1
  for (int tap = 0; tap < 9; ++tap) {
    const int dh = tap / 3 - 1, dw = tap % 3 - 1;
    const size_t aoff = (size_t)tap * 512 * 512;
    const int boff = (dh * 34 + dw) * 512;
#pragma unroll 1
    for (int k0 = 0; k0 < 512; k0 += 128) {
      __syncthreads();  // previous compute done before overwrite
#pragma unroll
      for (int c = 0; c < 4; ++c) {
        const int kq = k0 + c * 32;
        gld16(gA0 + aoff + kq, As + c * 4096 + wofs);
        gld16(gA1 + aoff + kq, As + c * 4096 + 2048 + wofs);
        gld16(gB0 + boff + kq, Bs + c * 4096 + wofs);
        gld16(gB1 + boff + kq, Bs + c * 4096 + 2048 + wofs);
      }
      __syncthreads();  // staged tiles visible
#pragma unroll
      for (int c = 0; c < 4; ++c) {
        v8bf a[4], bfr[4];
#pragma unroll
        for (int i = 0; i < 4; ++i)
          a[i] = load8(&As[c * 4096 + (mh + i * 16 + l15) * 32 + quad * 8]);
#pragma unroll
        for (int j = 0; j < 4; ++j)
          bfr[j] = load8(&Bs[c * 4096 + (nh + j * 16 + l15) * 32 + quad * 8]);
#pragma unroll
        for (int i = 0; i < 4; ++i)
#pragma unroll
          for (int j = 0; j < 4; ++j) acc[i][j] = mfma16(a[i], bfr[j], acc[i][j]);
      }
    }
  }

#pragma unroll
  for (int i = 0; i < 4; ++i)
#pragma unroll
    for (int j = 0; j < 4; ++j)
#pragma unroll
      for (int r = 0; r < 4; ++r) {
        int o = mbase + mh + i * 16 + quad * 4 + r;
        int nn = nbase + nh + j * 16 + l15;
        int bb2 = nn >> 10, s = nn & 1023;
        size_t idx = ((size_t)bb2 * 512 + o) * 1024 + s;
        out[idx] = acc[i][j][r] + bias[o] + x2[idx];
      }
}

// ------------------------------------------------------------------
extern "C" void kernel_launch(void* const* d_in, const int* in_sizes, int n_in,
                              void* d_out, int out_size, void* d_ws, size_t ws_size,
                              hipStream_t stream) {
  const float* x    = (const float*)d_in[0];
  const float* wqk  = (const float*)d_in[1];
  const float* wv   = (const float*)d_in[2];
  const float* relh = (const float*)d_in[3];
  const float* relw = (const float*)d_in[4];
  const float* g1   = (const float*)d_in[5];
  const float* b1   = (const float*)d_in[6];
  const float* m1   = (const float*)d_in[7];
  const float* v1   = (const float*)d_in[8];
  const float* g2   = (const float*)d_in[9];
  const float* b2   = (const float*)d_in[10];
  const float* m2   = (const float*)d_in[11];
  const float* v2   = (const float*)d_in[12];
  const float* wfc  = (const float*)d_in[13];
  const float* bfc  = (const float*)d_in[14];
  float* out = (float*)d_out;

  char* p = (char*)d_ws;
  __bf16* y    = (__bf16*)p; p += (size_t)8 * 1024 * 512 * 2;       // (b,s,c)
  __bf16* qb   = (__bf16*)p; p += (size_t)8 * 4 * 1024 * 128 * 2;   // (b,n,s,d)
  __bf16* kb   = (__bf16*)p; p += (size_t)8 * 4 * 1024 * 128 * 2;   // (b,n,s,d)
  __bf16* vb   = (__bf16*)p; p += (size_t)8 * 4 * 1024 * 128 * 2;   // (b,n,d,s)
  __bf16* Wt   = (__bf16*)p; p += (size_t)9 * 512 * 512 * 2;        // (tap,o,c)
  __bf16* wqkb = (__bf16*)p; p += (size_t)1024 * 512 * 2;           // [wall rows 0..1023]
  __bf16* wvb  = (__bf16*)p; p += (size_t)512 * 512 * 2;            // [wall rows 1024..1535]
  __bf16* rhb  = (__bf16*)p; p += 32768;
  __bf16* rwb  = (__bf16*)p; p += 32768;
  float*  x2   = (float*)p;  p += (size_t)8 * 512 * 1024 * 4;       // (b,c,s) fp32
  __bf16* zpad = (__bf16*)p; p += (size_t)8 * 34 * 34 * 512 * 2;    // padded z

  k_cast<<<dim3((1024 * 512 + 255) / 256), dim3(256), 0, stream>>>(wqk, wqkb, 1024 * 512);
  k_cast<<<dim3((512 * 512 + 255) / 256), dim3(256), 0, stream>>>(wv, wvb, 512 * 512);
  k_cast<<<dim3((63 * 128 + 255) / 256), dim3(256), 0, stream>>>(relh, rhb, 63 * 128);
  k_cast<<<dim3((63 * 128 + 255) / 256), dim3(256), 0, stream>>>(relw, rwb, 63 * 128);
  k_repack<<<dim3(512 * 512 / 256), dim3(256), 0, stream>>>(wfc, Wt);
  k_zero<<<dim3(591872 / 256), dim3(256), 0, stream>>>((float*)zpad);
  k_bn1<<<dim3(32, 16, 8), dim3(32, 8), 0, stream>>>(x, g1, b1, m1, v1, y);
  k_proj<<<dim3(12, 64), dim3(256), 0, stream>>>(wqkb, y, qb, kb, vb);
  k_attn<<<dim3(512), dim3(256), 0, stream>>>(qb, kb, vb, rhb, rwb, x, x2);
  k_bn2<<<dim3(32, 16, 8), dim3(32, 8), 0, stream>>>(x2, g2, b2, m2, v2, zpad);
  k_conv<<<dim3(4, 64, 1), dim3(256), 0, stream>>>(Wt, zpad, bfc, x2, out);
}

// Round 9
// 241.634 us; speedup vs baseline: 1.8642x; 1.1169x over previous
//
#include <hip/hip_runtime.h>

typedef __bf16 v8bf __attribute__((ext_vector_type(8)));
typedef float f32x4 __attribute__((ext_vector_type(4)));

#define DEVI static __device__ __forceinline__

DEVI v8bf load8(const __bf16* p) { return *reinterpret_cast<const v8bf*>(p); }

DEVI f32x4 mfma16(v8bf a, v8bf b, f32x4 c) {
  return __builtin_amdgcn_mfma_f32_16x16x32_bf16(a, b, c, 0, 0, 0);
}

// async global -> LDS, 16 bytes per lane. LDS dest: wave-uniform base + lane*16.
DEVI void gld16(const __bf16* g, __bf16* l) {
  __builtin_amdgcn_global_load_lds(
      (const __attribute__((address_space(1))) unsigned int*)(const void*)g,
      (__attribute__((address_space(3))) unsigned int*)(void*)l, 16, 0, 0);
}

#define SCALE_Q 0.08838834764831845f  // 128^-0.5

// ------------------------------------------------------------------
// Fused prologue: casts (wqk, wv, relh, relw), conv-weight repack, zpad zero.
// One launch instead of six.
//   blocks [0,2048)    : cast wqk  (524288)
//   blocks [2048,3072) : cast wv   (262144)
//   blocks [3072,3104) : cast relh (8064)
//   blocks [3104,3136) : cast relw (8064)
//   blocks [3136,4160) : repack Wt (262144 (o,c) pairs x 9 taps)
//   blocks [4160,6472) : zero zpad (591872 x 16B)
// ------------------------------------------------------------------
__global__ void k_prep(const float* __restrict__ wqk, const float* __restrict__ wv,
                       const float* __restrict__ relh, const float* __restrict__ relw,
                       const float* __restrict__ wfc, __bf16* __restrict__ wqkb,
                       __bf16* __restrict__ wvb, __bf16* __restrict__ rhb,
                       __bf16* __restrict__ rwb, __bf16* __restrict__ Wt,
                       float* __restrict__ zpad4) {
  const int bid = blockIdx.x, tid = threadIdx.x;
  if (bid < 2048) {
    int i = bid * 256 + tid;
    wqkb[i] = (__bf16)wqk[i];
  } else if (bid < 3072) {
    int i = (bid - 2048) * 256 + tid;
    wvb[i] = (__bf16)wv[i];
  } else if (bid < 3104) {
    int i = (bid - 3072) * 256 + tid;
    if (i < 8064) rhb[i] = (__bf16)relh[i];
  } else if (bid < 3136) {
    int i = (bid - 3104) * 256 + tid;
    if (i < 8064) rwb[i] = (__bf16)relw[i];
  } else if (bid < 4160) {
    int i = (bid - 3136) * 256 + tid;    // (o,c) pair
    const float* src = wfc + (size_t)i * 9;
#pragma unroll
    for (int tap = 0; tap < 9; ++tap)
      Wt[(size_t)tap * 262144 + i] = (__bf16)src[tap];
  } else {
    int i = (bid - 4160) * 256 + tid;
    f32x4 z = {0.f, 0.f, 0.f, 0.f};
    reinterpret_cast<f32x4*>(zpad4)[i] = z;
  }
}

// ------------------------------------------------------------------
// BN1 + ReLU on fp32 x, transpose (b,c,s) -> (b,s,c), bf16 out
// ------------------------------------------------------------------
__global__ void k_bn1(const float* __restrict__ x, const float* __restrict__ g,
                      const float* __restrict__ bb, const float* __restrict__ m,
                      const float* __restrict__ v, __bf16* __restrict__ y) {
  __shared__ float tile[32][33];
  const int b = blockIdx.z, c0 = blockIdx.y * 32, s0 = blockIdx.x * 32;
  const int tx = threadIdx.x, ty = threadIdx.y;   // 32 x 8
#pragma unroll
  for (int r = 0; r < 4; ++r) {
    int c = c0 + ty + r * 8;
    float inv = g[c] * rsqrtf(v[c] + 1e-5f);
    float beta = bb[c] - m[c] * inv;
    float val = x[((size_t)b * 512 + c) * 1024 + s0 + tx] * inv + beta;
    tile[ty + r * 8][tx] = fmaxf(val, 0.0f);
  }
  __syncthreads();
#pragma unroll
  for (int r = 0; r < 4; ++r) {
    int s = s0 + ty + r * 8;
    y[((size_t)b * 1024 + s) * 512 + c0 + tx] = (__bf16)tile[tx][ty + r * 8];
  }
}

// ------------------------------------------------------------------
// BN2 + ReLU on fp32 x2, transpose (b,c,s) -> padded (b,34,34,c), bf16 out
// ------------------------------------------------------------------
__global__ void k_bn2(const float* __restrict__ x2, const float* __restrict__ g,
                      const float* __restrict__ bb, const float* __restrict__ m,
                      const float* __restrict__ v, __bf16* __restrict__ zp) {
  __shared__ float tile[32][33];
  const int b = blockIdx.z, c0 = blockIdx.y * 32, s0 = blockIdx.x * 32;
  const int tx = threadIdx.x, ty = threadIdx.y;
#pragma unroll
  for (int r = 0; r < 4; ++r) {
    int c = c0 + ty + r * 8;
    float inv = g[c] * rsqrtf(v[c] + 1e-5f);
    float beta = bb[c] - m[c] * inv;
    float val = x2[((size_t)b * 512 + c) * 1024 + s0 + tx] * inv + beta;
    tile[ty + r * 8][tx] = fmaxf(val, 0.0f);
  }
  __syncthreads();
#pragma unroll
  for (int r = 0; r < 4; ++r) {
    int s = s0 + ty + r * 8;
    int hh = s >> 5, ww = s & 31;
    zp[(((size_t)b * 34 + hh + 1) * 34 + ww + 1) * 512 + c0 + tx] =
        (__bf16)tile[tx][ty + r * 8];
  }
}

// ------------------------------------------------------------------
// QKV projection, m97 structure: 128x128 tile, BK=32, global_load_lds.
// ------------------------------------------------------------------
__global__ __launch_bounds__(256) void k_proj(
    const __bf16* __restrict__ wall, const __bf16* __restrict__ y,
    __bf16* __restrict__ qout, __bf16* __restrict__ kout,
    __bf16* __restrict__ vout) {
  __shared__ __bf16 As[128 * 32];
  __shared__ __bf16 Bs[128 * 32];
  const int t = threadIdx.x;
  const int wave = t >> 6, lane = t & 63;
  const int l15 = lane & 15, quad = lane >> 4;
  const int mbase = blockIdx.x * 128;   // o in [0,1536)
  const int nbase = blockIdx.y * 128;   // flat (b,s)
  const int mh = (wave >> 1) * 64, nh = (wave & 1) * 64;

  const int row0 = t >> 2, part8 = (t & 3) * 8;
  const __bf16* gA0 = wall + (size_t)(mbase + row0) * 512 + part8;
  const __bf16* gA1 = gA0 + (size_t)64 * 512;
  const __bf16* gB0 = y + (size_t)(nbase + row0) * 512 + part8;
  const __bf16* gB1 = gB0 + (size_t)64 * 512;
  __bf16* lA0 = As + (size_t)(wave * 64) * 8;
  __bf16* lA1 = As + (size_t)(256 + wave * 64) * 8;
  __bf16* lB0 = Bs + (size_t)(wave * 64) * 8;
  __bf16* lB1 = Bs + (size_t)(256 + wave * 64) * 8;

  const f32x4 fz = {0.f, 0.f, 0.f, 0.f};
  f32x4 acc[4][4];
#pragma unroll
  for (int i = 0; i < 4; ++i)
#pragma unroll
    for (int j = 0; j < 4; ++j) acc[i][j] = fz;

  for (int k0 = 0; k0 < 512; k0 += 32) {
    __syncthreads();
    gld16(gA0 + k0, lA0);
    gld16(gA1 + k0, lA1);
    gld16(gB0 + k0, lB0);
    gld16(gB1 + k0, lB1);
    __syncthreads();
    v8bf a[4], bfr[4];
#pragma unroll
    for (int i = 0; i < 4; ++i)
      a[i] = load8(&As[(size_t)(mh + i * 16 + l15) * 32 + quad * 8]);
#pragma unroll
    for (int j = 0; j < 4; ++j)
      bfr[j] = load8(&Bs[(size_t)(nh + j * 16 + l15) * 32 + quad * 8]);
#pragma unroll
    for (int i = 0; i < 4; ++i)
#pragma unroll
      for (int j = 0; j < 4; ++j) acc[i][j] = mfma16(a[i], bfr[j], acc[i][j]);
  }

#pragma unroll
  for (int i = 0; i < 4; ++i)
#pragma unroll
    for (int j = 0; j < 4; ++j)
#pragma unroll
      for (int r = 0; r < 4; ++r) {
        int o = mbase + mh + i * 16 + quad * 4 + r;
        int nflat = nbase + nh + j * 16 + l15;
        int b = nflat >> 10, s = nflat & 1023;
        float val = acc[i][j][r];
        if (o < 512) {
          int n = o >> 7, d = o & 127;
          qout[(((size_t)b * 4 + n) * 1024 + s) * 128 + d] = (__bf16)(val * SCALE_Q);
        } else if (o < 1024) {
          int oe = o - 512; int n = oe >> 7, d = oe & 127;
          kout[(((size_t)b * 4 + n) * 1024 + s) * 128 + d] = (__bf16)val;
        } else {
          int oe = o - 1024; int n = oe >> 7, d = oe & 127;
          vout[(((size_t)b * 4 + n) * 128 + d) * 1024 + s] = (__bf16)val;
        }
      }
}

// ------------------------------------------------------------------
// Flash attention v4 (m97-structured) — unchanged from round 7.
// ------------------------------------------------------------------
__global__ __launch_bounds__(256, 2) void k_attn(
    const __bf16* __restrict__ q, const __bf16* __restrict__ kmat,
    const __bf16* __restrict__ vt, const __bf16* __restrict__ relh,
    const __bf16* __restrict__ relw, const float* __restrict__ x,
    float* __restrict__ x2) {
  __shared__ __bf16 Ks[4 * 64 * 32];
  __shared__ __bf16 Vs[2 * 128 * 32];
  __shared__ __bf16 P[4 * 16 * 72];
  __shared__ float RWs[64][33];
  __shared__ float RHs[64][33];

  const int Lb = blockIdx.x;             // 0..511
  const int xcd = Lb & 7, local = Lb >> 3;
  const int bn = xcd * 4 + (local & 3);
  const int qblk = local >> 2;           // 0..15
  const int s0 = qblk * 64;

  const int t = threadIdx.x;
  const int wave = t >> 6, lane = t & 63;
  const int l15 = lane & 15, quad = lane >> 4;
  const size_t hoff = ((size_t)bn) << 17;
  const int s0w = s0 + wave * 16;
  const int wlo = (wave & 1) * 16;
  const int h0w = s0w >> 5;

  v8bf aq[4];
  {
    const __bf16* qp = q + hoff + (size_t)(s0w + l15) * 128;
#pragma unroll
    for (int kk = 0; kk < 4; ++kk) aq[kk] = load8(qp + kk * 32 + quad * 8);
  }

#pragma unroll
  for (int nt = 0; nt < 4; ++nt) {
    int rr = nt * 16 + l15;
    const __bf16* bp = relw + (size_t)rr * 128;
    f32x4 acc = {0.f, 0.f, 0.f, 0.f};
#pragma unroll
    for (int kk = 0; kk < 4; ++kk)
      acc = mfma16(aq[kk], load8(bp + kk * 32 + quad * 8), acc);
#pragma unroll
    for (int r = 0; r < 4; ++r) {
      int row = quad * 4 + r;
      int wj = rr + wlo + row - 31;
      if (wj >= 0 && wj < 32) RWs[wave * 16 + row][wj] = acc[r];
    }
  }
#pragma unroll
  for (int nt = 0; nt < 2; ++nt) {
    int hj = nt * 16 + l15;
    const __bf16* bp = relh + (size_t)(hj - h0w + 31) * 128;
    f32x4 acc = {0.f, 0.f, 0.f, 0.f};
#pragma unroll
    for (int kk = 0; kk < 4; ++kk)
      acc = mfma16(aq[kk], load8(bp + kk * 32 + quad * 8), acc);
#pragma unroll
    for (int r = 0; r < 4; ++r) RHs[wave * 16 + quad * 4 + r][hj] = acc[r];
  }

  const int row0 = t >> 2, part8 = (t & 3) * 8;
  const __bf16* kg = kmat + hoff + (size_t)row0 * 128 + part8;
  const __bf16* vg = vt + hoff + (size_t)row0 * 1024 + part8;
  __bf16* ksw = Ks + wave * 512;
  __bf16* vsw = Vs + wave * 512;

  const f32x4 fz = {0.f, 0.f, 0.f, 0.f};
  float lsum[4] = {0.f, 0.f, 0.f, 0.f};
  f32x4 oacc[8];
#pragma unroll
  for (int dt = 0; dt < 8; ++dt) oacc[dt] = fz;
  __bf16* Pw = P + wave * 16 * 72;

#pragma unroll 1
  for (int iter = 0; iter < 16; ++iter) {
    const int j0 = iter * 64;
    __syncthreads();
#pragma unroll
    for (int kk = 0; kk < 4; ++kk)
      gld16(kg + (size_t)j0 * 128 + kk * 32, ksw + kk * 2048);
#pragma unroll
    for (int kk2 = 0; kk2 < 2; ++kk2)
#pragma unroll
      for (int dh = 0; dh < 2; ++dh)
        gld16(vg + (size_t)dh * 64 * 1024 + j0 + kk2 * 32,
              vsw + kk2 * 4096 + dh * 2048);
    __syncthreads();

    f32x4 sacc[4];
#pragma unroll
    for (int nj = 0; nj < 4; ++nj) {
      f32x4 a = fz;
#pragma unroll
      for (int kk = 0; kk < 4; ++kk)
        a = mfma16(aq[kk],
                   load8(&Ks[kk * 2048 + (nj * 16 + l15) * 32 + quad * 8]), a);
      sacc[nj] = a;
    }
#pragma unroll
    for (int nj = 0; nj < 4; ++nj) {
      const int wj = (nj & 1) * 16 + l15;
      const int hj = (j0 + nj * 16) >> 5;
#pragma unroll
      for (int r = 0; r < 4; ++r) {
        const int row = quad * 4 + r;
        const int gi = wave * 16 + row;
        float val = sacc[nj][r] + RWs[gi][wj] + RHs[gi][hj];
        float p = __expf(fminf(val, 60.0f));
        lsum[r] += p;
        Pw[row * 72 + nj * 16 + l15] = (__bf16)p;
      }
    }
    v8bf pf[2];
#pragma unroll
    for (int kk2 = 0; kk2 < 2; ++kk2)
      pf[kk2] = *reinterpret_cast<const v8bf*>(&Pw[l15 * 72 + kk2 * 32 + quad * 8]);
#pragma unroll
    for (int dt = 0; dt < 8; ++dt) {
      f32x4 a = oacc[dt];
#pragma unroll
      for (int kk2 = 0; kk2 < 2; ++kk2)
        a = mfma16(pf[kk2],
                   load8(&Vs[kk2 * 4096 + (dt * 16 + l15) * 32 + quad * 8]), a);
      oacc[dt] = a;
    }
  }

#pragma unroll
  for (int r = 0; r < 4; ++r)
#pragma unroll
    for (int msk = 8; msk >= 1; msk >>= 1) lsum[r] += __shfl_xor(lsum[r], msk);

#pragma unroll
  for (int r = 0; r < 4; ++r) {
    float inv = 1.0f / lsum[r];
    int s = s0w + quad * 4 + r;
#pragma unroll
    for (int dt = 0; dt < 8; ++dt) {
      int d = dt * 16 + l15;
      size_t idx = ((size_t)bn * 128 + d) * 1024 + s;
      x2[idx] = oacc[dt][r] * inv + x[idx];
    }
  }
}

// ------------------------------------------------------------------
// 3x3 conv, split-K=2 over channels: 512 blocks -> 2 blocks/CU so one
// block's MFMA hides the other's barrier drain (m114 overlap). XCD swizzle
// id&7 -> (o-tile, split): each XCD touches a 0.59 MB Wt slice + one z
// channel-half -> near L2-resident drains. BK=128 (4 m97-layout chunks),
// 18 iterations. Blocks write raw fp32 partials; k_sum merges.
// ------------------------------------------------------------------
__global__ __launch_bounds__(256, 2) void k_conv(
    const __bf16* __restrict__ Wt, const __bf16* __restrict__ zp,
    float* __restrict__ part) {
  __shared__ __bf16 As[4 * 128 * 32];   // 32 KB
  __shared__ __bf16 Bs[4 * 128 * 32];   // 32 KB
  const int t = threadIdx.x;
  const int wave = t >> 6, lane = t & 63;
  const int l15 = lane & 15, quad = lane >> 4;

  const int id = blockIdx.x;            // 0..511
  const int combo = id & 7;             // XCD-resident (o-tile, split)
  const int ot = combo >> 1, sp = combo & 1;
  const int nt = id >> 3;               // 0..63
  const int mbase = ot * 128;
  const int nbase = nt * 128;
  const int cs = sp * 256;              // channel half
  const int mh = (wave >> 1) * 64, nh = (wave & 1) * 64;

  const int row0 = t >> 2;              // [0,64)
  const int part8 = (t & 3) * 8;
  const __bf16* gA0 = Wt + (size_t)(mbase + row0) * 512 + cs + part8;
  const __bf16* gA1 = gA0 + (size_t)64 * 512;
  const int n0 = nbase + row0;
  const int b0 = n0 >> 10, spn = n0 & 1023;
  const __bf16* gB0 =
      zp + ((size_t)(b0 * 34 + (spn >> 5) + 1) * 34 + (spn & 31) + 1) * 512 + cs + part8;
  const __bf16* gB1 = gB0 + (size_t)2 * 34 * 512;   // spatial +64 -> h+2
  const int wofs = wave * 512;

  const f32x4 fz = {0.f, 0.f, 0.f, 0.f};
  f32x4 acc[4][4];
#pragma unroll
  for (int i = 0; i < 4; ++i)
#pragma unroll
    for (int j = 0; j < 4; ++j) acc[i][j] = fz;

#pragma unroll 1
  for (int tap = 0; tap < 9; ++tap) {
    const int dh = tap / 3 - 1, dw = tap % 3 - 1;
    const size_t aoff = (size_t)tap * 512 * 512;
    const int boff = (dh * 34 + dw) * 512;
#pragma unroll 1
    for (int k0 = 0; k0 < 256; k0 += 128) {
      __syncthreads();
#pragma unroll
      for (int c = 0; c < 4; ++c) {
        const int kq = k0 + c * 32;
        gld16(gA0 + aoff + kq, As + c * 4096 + wofs);
        gld16(gA1 + aoff + kq, As + c * 4096 + 2048 + wofs);
        gld16(gB0 + boff + kq, Bs + c * 4096 + wofs);
        gld16(gB1 + boff + kq, Bs + c * 4096 + 2048 + wofs);
      }
      __syncthreads();
#pragma unroll
      for (int c = 0; c < 4; ++c) {
        v8bf a[4], bfr[4];
#pragma unroll
        for (int i = 0; i < 4; ++i)
          a[i] = load8(&As[c * 4096 + (mh + i * 16 + l15) * 32 + quad * 8]);
#pragma unroll
        for (int j = 0; j < 4; ++j)
          bfr[j] = load8(&Bs[c * 4096 + (nh + j * 16 + l15) * 32 + quad * 8]);
#pragma unroll
        for (int i = 0; i < 4; ++i)
#pragma unroll
          for (int j = 0; j < 4; ++j) acc[i][j] = mfma16(a[i], bfr[j], acc[i][j]);
      }
    }
  }

  float* pout = part + (size_t)sp * 8 * 512 * 1024;
#pragma unroll
  for (int i = 0; i < 4; ++i)
#pragma unroll
    for (int j = 0; j < 4; ++j)
#pragma unroll
      for (int r = 0; r < 4; ++r) {
        int o = mbase + mh + i * 16 + quad * 4 + r;
        int nn = nbase + nh + j * 16 + l15;
        int bb2 = nn >> 10, s = nn & 1023;
        pout[((size_t)bb2 * 512 + o) * 1024 + s] = acc[i][j][r];
      }
}

// ------------------------------------------------------------------
// out = part0 + part1 + bias + x2   (f32x4 vectorized; 1048576 chunks)
// ------------------------------------------------------------------
__global__ void k_sum(const float* __restrict__ part, const float* __restrict__ bias,
                      const float* __restrict__ x2, float* __restrict__ out) {
  int i = blockIdx.x * 256 + threadIdx.x;
  int o = (i >> 8) & 511;
  f32x4 p0 = reinterpret_cast<const f32x4*>(part)[i];
  f32x4 p1 = reinterpret_cast<const f32x4*>(part + (size_t)8 * 512 * 1024)[i];
  f32x4 xr = reinterpret_cast<const f32x4*>(x2)[i];
  float bo = bias[o];
  f32x4 r;
#pragma unroll
  for (int c = 0; c < 4; ++c) r[c] = p0[c] + p1[c] + bo + xr[c];
  reinterpret_cast<f32x4*>(out)[i] = r;
}

// ------------------------------------------------------------------
extern "C" void kernel_launch(void* const* d_in, const int* in_sizes, int n_in,
                              void* d_out, int out_size, void* d_ws, size_t ws_size,
                              hipStream_t stream) {
  const float* x    = (const float*)d_in[0];
  const float* wqk  = (const float*)d_in[1];
  const float* wv   = (const float*)d_in[2];
  const float* relh = (const float*)d_in[3];
  const float* relw = (const float*)d_in[4];
  const float* g1   = (const float*)d_in[5];
  const float* b1   = (const float*)d_in[6];
  const float* m1   = (const float*)d_in[7];
  const float* v1   = (const float*)d_in[8];
  const float* g2   = (const float*)d_in[9];
  const float* b2   = (const float*)d_in[10];
  const float* m2   = (const float*)d_in[11];
  const float* v2   = (const float*)d_in[12];
  const float* wfc  = (const float*)d_in[13];
  const float* bfc  = (const float*)d_in[14];
  float* out = (float*)d_out;

  char* p = (char*)d_ws;
  __bf16* y    = (__bf16*)p; p += (size_t)8 * 1024 * 512 * 2;       // (b,s,c)
  __bf16* qb   = (__bf16*)p; p += (size_t)8 * 4 * 1024 * 128 * 2;   // (b,n,s,d)
  __bf16* kb   = (__bf16*)p; p += (size_t)8 * 4 * 1024 * 128 * 2;   // (b,n,s,d)
  __bf16* vb   = (__bf16*)p; p += (size_t)8 * 4 * 1024 * 128 * 2;   // (b,n,d,s)
  __bf16* Wt   = (__bf16*)p; p += (size_t)9 * 512 * 512 * 2;        // (tap,o,c)
  __bf16* wqkb = (__bf16*)p; p += (size_t)1024 * 512 * 2;           // wall rows 0..1023
  __bf16* wvb  = (__bf16*)p; p += (size_t)512 * 512 * 2;            // wall rows 1024..1535
  __bf16* rhb  = (__bf16*)p; p += 32768;
  __bf16* rwb  = (__bf16*)p; p += 32768;
  float*  x2   = (float*)p;  p += (size_t)8 * 512 * 1024 * 4;       // (b,c,s) fp32
  __bf16* zpad = (__bf16*)p; p += (size_t)8 * 34 * 34 * 512 * 2;    // padded z
  // fp32 conv partials (2 x 16.78 MB) alias y+qb+kb+vb (dead after k_attn)
  float* part = (float*)d_ws;

  k_prep<<<dim3(6472), dim3(256), 0, stream>>>(wqk, wv, relh, relw, wfc,
                                               wqkb, wvb, rhb, rwb, Wt, (float*)zpad);
  k_bn1<<<dim3(32, 16, 8), dim3(32, 8), 0, stream>>>(x, g1, b1, m1, v1, y);
  k_proj<<<dim3(12, 64), dim3(256), 0, stream>>>(wqkb, y, qb, kb, vb);
  k_attn<<<dim3(512), dim3(256), 0, stream>>>(qb, kb, vb, rhb, rwb, x, x2);
  k_bn2<<<dim3(32, 16, 8), dim3(32, 8), 0, stream>>>(x2, g2, b2, m2, v2, zpad);
  k_conv<<<dim3(512), dim3(256), 0, stream>>>(Wt, zpad, part);
  k_sum<<<dim3(4096), dim3(256), 0, stream>>>(part, bfc, x2, out);
}

// Round 10
// 240.773 us; speedup vs baseline: 1.8709x; 1.0036x over previous
//
#include <hip/hip_runtime.h>

typedef __bf16 v8bf __attribute__((ext_vector_type(8)));
typedef float f32x4 __attribute__((ext_vector_type(4)));

#define DEVI static __device__ __forceinline__

DEVI v8bf load8(const __bf16* p) { return *reinterpret_cast<const v8bf*>(p); }

DEVI f32x4 mfma16(v8bf a, v8bf b, f32x4 c) {
  return __builtin_amdgcn_mfma_f32_16x16x32_bf16(a, b, c, 0, 0, 0);
}

// async global -> LDS, 16 bytes per lane. LDS dest: wave-uniform base + lane*16.
DEVI void gld16(const __bf16* g, __bf16* l) {
  __builtin_amdgcn_global_load_lds(
      (const __attribute__((address_space(1))) unsigned int*)(const void*)g,
      (__attribute__((address_space(3))) unsigned int*)(void*)l, 16, 0, 0);
}

#define SCALE_Q 0.08838834764831845f  // 128^-0.5

// ------------------------------------------------------------------
// Fused prologue: casts, conv-weight repack, zpad zero. One launch.
// ------------------------------------------------------------------
__global__ void k_prep(const float* __restrict__ wqk, const float* __restrict__ wv,
                       const float* __restrict__ relh, const float* __restrict__ relw,
                       const float* __restrict__ wfc, __bf16* __restrict__ wqkb,
                       __bf16* __restrict__ wvb, __bf16* __restrict__ rhb,
                       __bf16* __restrict__ rwb, __bf16* __restrict__ Wt,
                       float* __restrict__ zpad4) {
  const int bid = blockIdx.x, tid = threadIdx.x;
  if (bid < 2048) {
    int i = bid * 256 + tid;
    wqkb[i] = (__bf16)wqk[i];
  } else if (bid < 3072) {
    int i = (bid - 2048) * 256 + tid;
    wvb[i] = (__bf16)wv[i];
  } else if (bid < 3104) {
    int i = (bid - 3072) * 256 + tid;
    if (i < 8064) rhb[i] = (__bf16)relh[i];
  } else if (bid < 3136) {
    int i = (bid - 3104) * 256 + tid;
    if (i < 8064) rwb[i] = (__bf16)relw[i];
  } else if (bid < 4160) {
    int i = (bid - 3136) * 256 + tid;    // (o,c) pair
    const float* src = wfc + (size_t)i * 9;
#pragma unroll
    for (int tap = 0; tap < 9; ++tap)
      Wt[(size_t)tap * 262144 + i] = (__bf16)src[tap];
  } else {
    int i = (bid - 4160) * 256 + tid;
    f32x4 z = {0.f, 0.f, 0.f, 0.f};
    reinterpret_cast<f32x4*>(zpad4)[i] = z;
  }
}

// ------------------------------------------------------------------
// BN1 + ReLU on fp32 x, transpose (b,c,s) -> (b,s,c), bf16 out
// ------------------------------------------------------------------
__global__ void k_bn1(const float* __restrict__ x, const float* __restrict__ g,
                      const float* __restrict__ bb, const float* __restrict__ m,
                      const float* __restrict__ v, __bf16* __restrict__ y) {
  __shared__ float tile[32][33];
  const int b = blockIdx.z, c0 = blockIdx.y * 32, s0 = blockIdx.x * 32;
  const int tx = threadIdx.x, ty = threadIdx.y;   // 32 x 8
#pragma unroll
  for (int r = 0; r < 4; ++r) {
    int c = c0 + ty + r * 8;
    float inv = g[c] * rsqrtf(v[c] + 1e-5f);
    float beta = bb[c] - m[c] * inv;
    float val = x[((size_t)b * 512 + c) * 1024 + s0 + tx] * inv + beta;
    tile[ty + r * 8][tx] = fmaxf(val, 0.0f);
  }
  __syncthreads();
#pragma unroll
  for (int r = 0; r < 4; ++r) {
    int s = s0 + ty + r * 8;
    y[((size_t)b * 1024 + s) * 512 + c0 + tx] = (__bf16)tile[tx][ty + r * 8];
  }
}

// ------------------------------------------------------------------
// BN2 + ReLU on fp32 x2, transpose (b,c,s) -> padded (b,34,34,c), bf16 out
// ------------------------------------------------------------------
__global__ void k_bn2(const float* __restrict__ x2, const float* __restrict__ g,
                      const float* __restrict__ bb, const float* __restrict__ m,
                      const float* __restrict__ v, __bf16* __restrict__ zp) {
  __shared__ float tile[32][33];
  const int b = blockIdx.z, c0 = blockIdx.y * 32, s0 = blockIdx.x * 32;
  const int tx = threadIdx.x, ty = threadIdx.y;
#pragma unroll
  for (int r = 0; r < 4; ++r) {
    int c = c0 + ty + r * 8;
    float inv = g[c] * rsqrtf(v[c] + 1e-5f);
    float beta = bb[c] - m[c] * inv;
    float val = x2[((size_t)b * 512 + c) * 1024 + s0 + tx] * inv + beta;
    tile[ty + r * 8][tx] = fmaxf(val, 0.0f);
  }
  __syncthreads();
#pragma unroll
  for (int r = 0; r < 4; ++r) {
    int s = s0 + ty + r * 8;
    int hh = s >> 5, ww = s & 31;
    zp[(((size_t)b * 34 + hh + 1) * 34 + ww + 1) * 512 + c0 + tx] =
        (__bf16)tile[tx][ty + r * 8];
  }
}

// ------------------------------------------------------------------
// QKV projection, m97 structure. For q/k blocks (blockIdx.x < 8) the MFMA
// operands are SWAPPED (A = y-tile, B = weight-tile) so C is transposed:
// lane l15 then indexes o -> d-contiguous 32B store segments instead of the
// 256B-stride 2B scatter (was 39.7 MB WRITE vs 25 ideal). v blocks keep the
// original orientation (their store is s-contiguous already).
// ------------------------------------------------------------------
__global__ __launch_bounds__(256) void k_proj(
    const __bf16* __restrict__ wall, const __bf16* __restrict__ y,
    __bf16* __restrict__ qout, __bf16* __restrict__ kout,
    __bf16* __restrict__ vout) {
  __shared__ __bf16 As[128 * 32];
  __shared__ __bf16 Bs[128 * 32];
  const int t = threadIdx.x;
  const int wave = t >> 6, lane = t & 63;
  const int l15 = lane & 15, quad = lane >> 4;
  const int mbase = blockIdx.x * 128;   // o in [0,1536)
  const int nbase = blockIdx.y * 128;   // flat (b,s)
  const int mh = (wave >> 1) * 64, nh = (wave & 1) * 64;
  const bool isv = mbase >= 1024;

  const int row0 = t >> 2, part8 = (t & 3) * 8;
  const __bf16* gA0 = wall + (size_t)(mbase + row0) * 512 + part8;
  const __bf16* gA1 = gA0 + (size_t)64 * 512;
  const __bf16* gB0 = y + (size_t)(nbase + row0) * 512 + part8;
  const __bf16* gB1 = gB0 + (size_t)64 * 512;
  __bf16* lA0 = As + (size_t)(wave * 64) * 8;
  __bf16* lA1 = As + (size_t)(256 + wave * 64) * 8;
  __bf16* lB0 = Bs + (size_t)(wave * 64) * 8;
  __bf16* lB1 = Bs + (size_t)(256 + wave * 64) * 8;

  const f32x4 fz = {0.f, 0.f, 0.f, 0.f};
  f32x4 acc[4][4];
#pragma unroll
  for (int i = 0; i < 4; ++i)
#pragma unroll
    for (int j = 0; j < 4; ++j) acc[i][j] = fz;

  for (int k0 = 0; k0 < 512; k0 += 32) {
    __syncthreads();
    gld16(gA0 + k0, lA0);
    gld16(gA1 + k0, lA1);
    gld16(gB0 + k0, lB0);
    gld16(gB1 + k0, lB1);
    __syncthreads();
    v8bf a[4], bfr[4];
#pragma unroll
    for (int i = 0; i < 4; ++i)
      a[i] = load8(&As[(size_t)(mh + i * 16 + l15) * 32 + quad * 8]);
#pragma unroll
    for (int j = 0; j < 4; ++j)
      bfr[j] = load8(&Bs[(size_t)(nh + j * 16 + l15) * 32 + quad * 8]);
    if (isv) {
#pragma unroll
      for (int i = 0; i < 4; ++i)
#pragma unroll
        for (int j = 0; j < 4; ++j) acc[i][j] = mfma16(a[i], bfr[j], acc[i][j]);
    } else {
#pragma unroll
      for (int i = 0; i < 4; ++i)
#pragma unroll
        for (int j = 0; j < 4; ++j) acc[i][j] = mfma16(bfr[j], a[i], acc[i][j]);
    }
  }

  if (isv) {
    // original orientation: row = o(quad*4+r), col = s(l15)
#pragma unroll
    for (int i = 0; i < 4; ++i)
#pragma unroll
      for (int j = 0; j < 4; ++j)
#pragma unroll
        for (int r = 0; r < 4; ++r) {
          int o = mbase + mh + i * 16 + quad * 4 + r;
          int nflat = nbase + nh + j * 16 + l15;
          int b = nflat >> 10, s = nflat & 1023;
          int oe = o - 1024; int n = oe >> 7, d = oe & 127;
          vout[(((size_t)b * 4 + n) * 128 + d) * 1024 + s] = (__bf16)acc[i][j][r];
        }
  } else {
    // transposed: row = s(quad*4+r), col = o(l15) -> d-contiguous stores
    const bool isq = mbase < 512;
#pragma unroll
    for (int i = 0; i < 4; ++i)
#pragma unroll
      for (int j = 0; j < 4; ++j)
#pragma unroll
        for (int r = 0; r < 4; ++r) {
          int o = mbase + mh + i * 16 + l15;
          int nflat = nbase + nh + j * 16 + quad * 4 + r;
          int b = nflat >> 10, s = nflat & 1023;
          float val = acc[i][j][r];
          if (isq) {
            int n = o >> 7, d = o & 127;
            qout[(((size_t)b * 4 + n) * 1024 + s) * 128 + d] = (__bf16)(val * SCALE_Q);
          } else {
            int oe = o - 512; int n = oe >> 7, d = oe & 127;
            kout[(((size_t)b * 4 + n) * 1024 + s) * 128 + d] = (__bf16)val;
          }
        }
  }
}

// ------------------------------------------------------------------
// Flash attention v5: m97-staged K/V, per-wave 16 q-rows, c=0 softmax.
// LDS diet: bias tables bf16, P stride 68 -> 49.9 KB -> 3 blocks/CU.
// Hoisted bias loads: 4 scalar LDS reads per (iter,r) instead of 8.
// ------------------------------------------------------------------
__global__ __launch_bounds__(256, 3) void k_attn(
    const __bf16* __restrict__ q, const __bf16* __restrict__ kmat,
    const __bf16* __restrict__ vt, const __bf16* __restrict__ relh,
    const __bf16* __restrict__ relw, const float* __restrict__ x,
    float* __restrict__ x2) {
  __shared__ __bf16 Ks[4 * 64 * 32];    // 16 KB
  __shared__ __bf16 Vs[2 * 128 * 32];   // 16 KB
  __shared__ __bf16 P[4 * 16 * 68];     // 8.7 KB
  __shared__ __bf16 RWs[64][33];        // 4.2 KB
  __shared__ __bf16 RHs[64][33];        // 4.2 KB

  const int Lb = blockIdx.x;             // 0..511
  const int xcd = Lb & 7, local = Lb >> 3;
  const int bn = xcd * 4 + (local & 3);
  const int qblk = local >> 2;           // 0..15
  const int s0 = qblk * 64;

  const int t = threadIdx.x;
  const int wave = t >> 6, lane = t & 63;
  const int l15 = lane & 15, quad = lane >> 4;
  const size_t hoff = ((size_t)bn) << 17;
  const int s0w = s0 + wave * 16;
  const int wlo = (wave & 1) * 16;
  const int h0w = s0w >> 5;

  v8bf aq[4];
  {
    const __bf16* qp = q + hoff + (size_t)(s0w + l15) * 128;
#pragma unroll
    for (int kk = 0; kk < 4; ++kk) aq[kk] = load8(qp + kk * 32 + quad * 8);
  }

#pragma unroll
  for (int nt = 0; nt < 4; ++nt) {       // RWs via shift-write
    int rr = nt * 16 + l15;
    const __bf16* bp = relw + (size_t)rr * 128;
    f32x4 acc = {0.f, 0.f, 0.f, 0.f};
#pragma unroll
    for (int kk = 0; kk < 4; ++kk)
      acc = mfma16(aq[kk], load8(bp + kk * 32 + quad * 8), acc);
#pragma unroll
    for (int r = 0; r < 4; ++r) {
      int row = quad * 4 + r;
      int wj = rr + wlo + row - 31;
      if (wj >= 0 && wj < 32) RWs[wave * 16 + row][wj] = (__bf16)acc[r];
    }
  }
#pragma unroll
  for (int nt = 0; nt < 2; ++nt) {       // RHs direct
    int hj = nt * 16 + l15;
    const __bf16* bp = relh + (size_t)(hj - h0w + 31) * 128;
    f32x4 acc = {0.f, 0.f, 0.f, 0.f};
#pragma unroll
    for (int kk = 0; kk < 4; ++kk)
      acc = mfma16(aq[kk], load8(bp + kk * 32 + quad * 8), acc);
#pragma unroll
    for (int r = 0; r < 4; ++r) RHs[wave * 16 + quad * 4 + r][hj] = (__bf16)acc[r];
  }

  const int row0 = t >> 2, part8 = (t & 3) * 8;
  const __bf16* kg = kmat + hoff + (size_t)row0 * 128 + part8;
  const __bf16* vg = vt + hoff + (size_t)row0 * 1024 + part8;
  __bf16* ksw = Ks + wave * 512;
  __bf16* vsw = Vs + wave * 512;

  const f32x4 fz = {0.f, 0.f, 0.f, 0.f};
  float lsum[4] = {0.f, 0.f, 0.f, 0.f};
  f32x4 oacc[8];
#pragma unroll
  for (int dt = 0; dt < 8; ++dt) oacc[dt] = fz;
  __bf16* Pw = P + wave * 16 * 68;

#pragma unroll 1
  for (int iter = 0; iter < 16; ++iter) {
    const int j0 = iter * 64;
    __syncthreads();
#pragma unroll
    for (int kk = 0; kk < 4; ++kk)
      gld16(kg + (size_t)j0 * 128 + kk * 32, ksw + kk * 2048);
#pragma unroll
    for (int kk2 = 0; kk2 < 2; ++kk2)
#pragma unroll
      for (int dh = 0; dh < 2; ++dh)
        gld16(vg + (size_t)dh * 64 * 1024 + j0 + kk2 * 32,
              vsw + kk2 * 4096 + dh * 2048);
    __syncthreads();

    f32x4 sacc[4];
#pragma unroll
    for (int nj = 0; nj < 4; ++nj) {
      f32x4 a = fz;
#pragma unroll
      for (int kk = 0; kk < 4; ++kk)
        a = mfma16(aq[kk],
                   load8(&Ks[kk * 2048 + (nj * 16 + l15) * 32 + quad * 8]), a);
      sacc[nj] = a;
    }
    // bias (hoisted table loads) + exp(c=0) + partial l + stash P
    const int hjb = j0 >> 5;
#pragma unroll
    for (int r = 0; r < 4; ++r) {
      const int row = quad * 4 + r;
      const int gi = wave * 16 + row;
      const float rw0 = (float)RWs[gi][l15], rw1 = (float)RWs[gi][l15 + 16];
      const float rh0 = (float)RHs[gi][hjb], rh1 = (float)RHs[gi][hjb + 1];
#pragma unroll
      for (int nj = 0; nj < 4; ++nj) {
        float val = sacc[nj][r] + ((nj & 1) ? rw1 : rw0) + ((nj & 2) ? rh1 : rh0);
        float p = __expf(fminf(val, 60.0f));
        lsum[r] += p;
        Pw[row * 68 + nj * 16 + l15] = (__bf16)p;
      }
    }
    v8bf pf[2];
#pragma unroll
    for (int kk2 = 0; kk2 < 2; ++kk2)
      pf[kk2] = *reinterpret_cast<const v8bf*>(&Pw[l15 * 68 + kk2 * 32 + quad * 8]);
#pragma unroll
    for (int dt = 0; dt < 8; ++dt) {
      f32x4 a = oacc[dt];
#pragma unroll
      for (int kk2 = 0; kk2 < 2; ++kk2)
        a = mfma16(pf[kk2],
                   load8(&Vs[kk2 * 4096 + (dt * 16 + l15) * 32 + quad * 8]), a);
      oacc[dt] = a;
    }
  }

#pragma unroll
  for (int r = 0; r < 4; ++r)
#pragma unroll
    for (int msk = 8; msk >= 1; msk >>= 1) lsum[r] += __shfl_xor(lsum[r], msk);

#pragma unroll
  for (int r = 0; r < 4; ++r) {
    float inv = 1.0f / lsum[r];
    int s = s0w + quad * 4 + r;
#pragma unroll
    for (int dt = 0; dt < 8; ++dt) {
      int d = dt * 16 + l15;
      size_t idx = ((size_t)bn * 128 + d) * 1024 + s;
      x2[idx] = oacc[dt][r] * inv + x[idx];
    }
  }
}

// ------------------------------------------------------------------
// 3x3 conv, split-K=2 (unchanged from round 9): 512 blocks, 2/CU, XCD
// swizzle for L2-resident drains, BK=128, fp32 partials -> k_sum.
// ------------------------------------------------------------------
__global__ __launch_bounds__(256, 2) void k_conv(
    const __bf16* __restrict__ Wt, const __bf16* __restrict__ zp,
    float* __restrict__ part) {
  __shared__ __bf16 As[4 * 128 * 32];   // 32 KB
  __shared__ __bf16 Bs[4 * 128 * 32];   // 32 KB
  const int t = threadIdx.x;
  const int wave = t >> 6, lane = t & 63;
  const int l15 = lane & 15, quad = lane >> 4;

  const int id = blockIdx.x;            // 0..511
  const int combo = id & 7;
  const int ot = combo >> 1, sp = combo & 1;
  const int nt = id >> 3;
  const int mbase = ot * 128;
  const int nbase = nt * 128;
  const int cs = sp * 256;
  const int mh = (wave >> 1) * 64, nh = (wave & 1) * 64;

  const int row0 = t >> 2;
  const int part8 = (t & 3) * 8;
  const __bf16* gA0 = Wt + (size_t)(mbase + row0) * 512 + cs + part8;
  const __bf16* gA1 = gA0 + (size_t)64 * 512;
  const int n0 = nbase + row0;
  const int b0 = n0 >> 10, spn = n0 & 1023;
  const __bf16* gB0 =
      zp + ((size_t)(b0 * 34 + (spn >> 5) + 1) * 34 + (spn & 31) + 1) * 512 + cs + part8;
  const __bf16* gB1 = gB0 + (size_t)2 * 34 * 512;
  const int wofs = wave * 512;

  const f32x4 fz = {0.f, 0.f, 0.f, 0.f};
  f32x4 acc[4][4];
#pragma unroll
  for (int i = 0; i < 4; ++i)
#pragma unroll
    for (int j = 0; j < 4; ++j) acc[i][j] = fz;

#pragma unroll 1
  for (int tap = 0; tap < 9; ++tap) {
    const int dh = tap / 3 - 1, dw = tap % 3 - 1;
    const size_t aoff = (size_t)tap * 512 * 512;
    const int boff = (dh * 34 + dw) * 512;
#pragma unroll 1
    for (int k0 = 0; k0 < 256; k0 += 128) {
      __syncthreads();
#pragma unroll
      for (int c = 0; c < 4; ++c) {
        const int kq = k0 + c * 32;
        gld16(gA0 + aoff + kq, As + c * 4096 + wofs);
        gld16(gA1 + aoff + kq, As + c * 4096 + 2048 + wofs);
        gld16(gB0 + boff + kq, Bs + c * 4096 + wofs);
        gld16(gB1 + boff + kq, Bs + c * 4096 + 2048 + wofs);
      }
      __syncthreads();
#pragma unroll
      for (int c = 0; c < 4; ++c) {
        v8bf a[4], bfr[4];
#pragma unroll
        for (int i = 0; i < 4; ++i)
          a[i] = load8(&As[c * 4096 + (mh + i * 16 + l15) * 32 + quad * 8]);
#pragma unroll
        for (int j = 0; j < 4; ++j)
          bfr[j] = load8(&Bs[c * 4096 + (nh + j * 16 + l15) * 32 + quad * 8]);
#pragma unroll
        for (int i = 0; i < 4; ++i)
#pragma unroll
          for (int j = 0; j < 4; ++j) acc[i][j] = mfma16(a[i], bfr[j], acc[i][j]);
      }
    }
  }

  float* pout = part + (size_t)sp * 8 * 512 * 1024;
#pragma unroll
  for (int i = 0; i < 4; ++i)
#pragma unroll
    for (int j = 0; j < 4; ++j)
#pragma unroll
      for (int r = 0; r < 4; ++r) {
        int o = mbase + mh + i * 16 + quad * 4 + r;
        int nn = nbase + nh + j * 16 + l15;
        int bb2 = nn >> 10, s = nn & 1023;
        pout[((size_t)bb2 * 512 + o) * 1024 + s] = acc[i][j][r];
      }
}

// ------------------------------------------------------------------
// out = part0 + part1 + bias + x2   (f32x4 vectorized)
// ------------------------------------------------------------------
__global__ void k_sum(const float* __restrict__ part, const float* __restrict__ bias,
                      const float* __restrict__ x2, float* __restrict__ out) {
  int i = blockIdx.x * 256 + threadIdx.x;
  int o = (i >> 8) & 511;
  f32x4 p0 = reinterpret_cast<const f32x4*>(part)[i];
  f32x4 p1 = reinterpret_cast<const f32x4*>(part + (size_t)8 * 512 * 1024)[i];
  f32x4 xr = reinterpret_cast<const f32x4*>(x2)[i];
  float bo = bias[o];
  f32x4 r;
#pragma unroll
  for (int c = 0; c < 4; ++c) r[c] = p0[c] + p1[c] + bo + xr[c];
  reinterpret_cast<f32x4*>(out)[i] = r;
}

// ------------------------------------------------------------------
extern "C" void kernel_launch(void* const* d_in, const int* in_sizes, int n_in,
                              void* d_out, int out_size, void* d_ws, size_t ws_size,
                              hipStream_t stream) {
  const float* x    = (const float*)d_in[0];
  const float* wqk  = (const float*)d_in[1];
  const float* wv   = (const float*)d_in[2];
  const float* relh = (const float*)d_in[3];
  const float* relw = (const float*)d_in[4];
  const float* g1   = (const float*)d_in[5];
  const float* b1   = (const float*)d_in[6];
  const float* m1   = (const float*)d_in[7];
  const float* v1   = (const float*)d_in[8];
  const float* g2   = (const float*)d_in[9];
  const float* b2   = (const float*)d_in[10];
  const float* m2   = (const float*)d_in[11];
  const float* v2   = (const float*)d_in[12];
  const float* wfc  = (const float*)d_in[13];
  const float* bfc  = (const float*)d_in[14];
  float* out = (float*)d_out;

  char* p = (char*)d_ws;
  __bf16* y    = (__bf16*)p; p += (size_t)8 * 1024 * 512 * 2;       // (b,s,c)
  __bf16* qb   = (__bf16*)p; p += (size_t)8 * 4 * 1024 * 128 * 2;   // (b,n,s,d)
  __bf16* kb   = (__bf16*)p; p += (size_t)8 * 4 * 1024 * 128 * 2;   // (b,n,s,d)
  __bf16* vb   = (__bf16*)p; p += (size_t)8 * 4 * 1024 * 128 * 2;   // (b,n,d,s)
  __bf16* Wt   = (__bf16*)p; p += (size_t)9 * 512 * 512 * 2;        // (tap,o,c)
  __bf16* wqkb = (__bf16*)p; p += (size_t)1024 * 512 * 2;           // wall rows 0..1023
  __bf16* wvb  = (__bf16*)p; p += (size_t)512 * 512 * 2;            // wall rows 1024..1535
  __bf16* rhb  = (__bf16*)p; p += 32768;
  __bf16* rwb  = (__bf16*)p; p += 32768;
  float*  x2   = (float*)p;  p += (size_t)8 * 512 * 1024 * 4;       // (b,c,s) fp32
  __bf16* zpad = (__bf16*)p; p += (size_t)8 * 34 * 34 * 512 * 2;    // padded z
  // fp32 conv partials (2 x 16.78 MB) alias y+qb+kb+vb (dead after k_attn)
  float* part = (float*)d_ws;

  k_prep<<<dim3(6472), dim3(256), 0, stream>>>(wqk, wv, relh, relw, wfc,
                                               wqkb, wvb, rhb, rwb, Wt, (float*)zpad);
  k_bn1<<<dim3(32, 16, 8), dim3(32, 8), 0, stream>>>(x, g1, b1, m1, v1, y);
  k_proj<<<dim3(12, 64), dim3(256), 0, stream>>>(wqkb, y, qb, kb, vb);
  k_attn<<<dim3(512), dim3(256), 0, stream>>>(qb, kb, vb, rhb, rwb, x, x2);
  k_bn2<<<dim3(32, 16, 8), dim3(32, 8), 0, stream>>>(x2, g2, b2, m2, v2, zpad);
  k_conv<<<dim3(512), dim3(256), 0, stream>>>(Wt, zpad, part);
  k_sum<<<dim3(4096), dim3(256), 0, stream>>>(part, bfc, x2, out);
}

// Round 11
// 237.056 us; speedup vs baseline: 1.9002x; 1.0157x over previous
//
#include <hip/hip_runtime.h>

typedef __bf16 v8bf __attribute__((ext_vector_type(8)));
typedef float f32x4 __attribute__((ext_vector_type(4)));

#define DEVI static __device__ __forceinline__

DEVI v8bf load8(const __bf16* p) { return *reinterpret_cast<const v8bf*>(p); }

DEVI f32x4 mfma16(v8bf a, v8bf b, f32x4 c) {
  return __builtin_amdgcn_mfma_f32_16x16x32_bf16(a, b, c, 0, 0, 0);
}

// async global -> LDS, 16 bytes per lane. LDS dest: wave-uniform base + lane*16.
DEVI void gld16(const __bf16* g, __bf16* l) {
  __builtin_amdgcn_global_load_lds(
      (const __attribute__((address_space(1))) unsigned int*)(const void*)g,
      (__attribute__((address_space(3))) unsigned int*)(void*)l, 16, 0, 0);
}

#define SCALE_Q 0.08838834764831845f  // 128^-0.5

// ------------------------------------------------------------------
// Fused prologue: casts, conv-weight repack, zpad zero. One launch.
// ------------------------------------------------------------------
__global__ void k_prep(const float* __restrict__ wqk, const float* __restrict__ wv,
                       const float* __restrict__ relh, const float* __restrict__ relw,
                       const float* __restrict__ wfc, __bf16* __restrict__ wqkb,
                       __bf16* __restrict__ wvb, __bf16* __restrict__ rhb,
                       __bf16* __restrict__ rwb, __bf16* __restrict__ Wt,
                       float* __restrict__ zpad4) {
  const int bid = blockIdx.x, tid = threadIdx.x;
  if (bid < 2048) {
    int i = bid * 256 + tid;
    wqkb[i] = (__bf16)wqk[i];
  } else if (bid < 3072) {
    int i = (bid - 2048) * 256 + tid;
    wvb[i] = (__bf16)wv[i];
  } else if (bid < 3104) {
    int i = (bid - 3072) * 256 + tid;
    if (i < 8064) rhb[i] = (__bf16)relh[i];
  } else if (bid < 3136) {
    int i = (bid - 3104) * 256 + tid;
    if (i < 8064) rwb[i] = (__bf16)relw[i];
  } else if (bid < 4160) {
    int i = (bid - 3136) * 256 + tid;    // (o,c) pair
    const float* src = wfc + (size_t)i * 9;
#pragma unroll
    for (int tap = 0; tap < 9; ++tap)
      Wt[(size_t)tap * 262144 + i] = (__bf16)src[tap];
  } else {
    int i = (bid - 4160) * 256 + tid;
    f32x4 z = {0.f, 0.f, 0.f, 0.f};
    reinterpret_cast<f32x4*>(zpad4)[i] = z;
  }
}

// ------------------------------------------------------------------
// BN1 + ReLU on fp32 x, transpose (b,c,s) -> (b,s,c), bf16 out
// ------------------------------------------------------------------
__global__ void k_bn1(const float* __restrict__ x, const float* __restrict__ g,
                      const float* __restrict__ bb, const float* __restrict__ m,
                      const float* __restrict__ v, __bf16* __restrict__ y) {
  __shared__ float tile[32][33];
  const int b = blockIdx.z, c0 = blockIdx.y * 32, s0 = blockIdx.x * 32;
  const int tx = threadIdx.x, ty = threadIdx.y;   // 32 x 8
#pragma unroll
  for (int r = 0; r < 4; ++r) {
    int c = c0 + ty + r * 8;
    float inv = g[c] * rsqrtf(v[c] + 1e-5f);
    float beta = bb[c] - m[c] * inv;
    float val = x[((size_t)b * 512 + c) * 1024 + s0 + tx] * inv + beta;
    tile[ty + r * 8][tx] = fmaxf(val, 0.0f);
  }
  __syncthreads();
#pragma unroll
  for (int r = 0; r < 4; ++r) {
    int s = s0 + ty + r * 8;
    y[((size_t)b * 1024 + s) * 512 + c0 + tx] = (__bf16)tile[tx][ty + r * 8];
  }
}

// ------------------------------------------------------------------
// BN2 + ReLU on fp32 x2, transpose (b,c,s) -> padded (b,34,34,c), bf16 out
// ------------------------------------------------------------------
__global__ void k_bn2(const float* __restrict__ x2, const float* __restrict__ g,
                      const float* __restrict__ bb, const float* __restrict__ m,
                      const float* __restrict__ v, __bf16* __restrict__ zp) {
  __shared__ float tile[32][33];
  const int b = blockIdx.z, c0 = blockIdx.y * 32, s0 = blockIdx.x * 32;
  const int tx = threadIdx.x, ty = threadIdx.y;
#pragma unroll
  for (int r = 0; r < 4; ++r) {
    int c = c0 + ty + r * 8;
    float inv = g[c] * rsqrtf(v[c] + 1e-5f);
    float beta = bb[c] - m[c] * inv;
    float val = x2[((size_t)b * 512 + c) * 1024 + s0 + tx] * inv + beta;
    tile[ty + r * 8][tx] = fmaxf(val, 0.0f);
  }
  __syncthreads();
#pragma unroll
  for (int r = 0; r < 4; ++r) {
    int s = s0 + ty + r * 8;
    int hh = s >> 5, ww = s & 31;
    zp[(((size_t)b * 34 + hh + 1) * 34 + ww + 1) * 512 + c0 + tx] =
        (__bf16)tile[tx][ty + r * 8];
  }
}

// ------------------------------------------------------------------
// QKV projection, m97 structure. q/k blocks use swapped operands so the
// store is d-contiguous; v blocks keep original orientation (s-contiguous).
// ------------------------------------------------------------------
__global__ __launch_bounds__(256) void k_proj(
    const __bf16* __restrict__ wall, const __bf16* __restrict__ y,
    __bf16* __restrict__ qout, __bf16* __restrict__ kout,
    __bf16* __restrict__ vout) {
  __shared__ __bf16 As[128 * 32];
  __shared__ __bf16 Bs[128 * 32];
  const int t = threadIdx.x;
  const int wave = t >> 6, lane = t & 63;
  const int l15 = lane & 15, quad = lane >> 4;
  const int mbase = blockIdx.x * 128;   // o in [0,1536)
  const int nbase = blockIdx.y * 128;   // flat (b,s)
  const int mh = (wave >> 1) * 64, nh = (wave & 1) * 64;
  const bool isv = mbase >= 1024;

  const int row0 = t >> 2, part8 = (t & 3) * 8;
  const __bf16* gA0 = wall + (size_t)(mbase + row0) * 512 + part8;
  const __bf16* gA1 = gA0 + (size_t)64 * 512;
  const __bf16* gB0 = y + (size_t)(nbase + row0) * 512 + part8;
  const __bf16* gB1 = gB0 + (size_t)64 * 512;
  __bf16* lA0 = As + (size_t)(wave * 64) * 8;
  __bf16* lA1 = As + (size_t)(256 + wave * 64) * 8;
  __bf16* lB0 = Bs + (size_t)(wave * 64) * 8;
  __bf16* lB1 = Bs + (size_t)(256 + wave * 64) * 8;

  const f32x4 fz = {0.f, 0.f, 0.f, 0.f};
  f32x4 acc[4][4];
#pragma unroll
  for (int i = 0; i < 4; ++i)
#pragma unroll
    for (int j = 0; j < 4; ++j) acc[i][j] = fz;

  for (int k0 = 0; k0 < 512; k0 += 32) {
    __syncthreads();
    gld16(gA0 + k0, lA0);
    gld16(gA1 + k0, lA1);
    gld16(gB0 + k0, lB0);
    gld16(gB1 + k0, lB1);
    __syncthreads();
    v8bf a[4], bfr[4];
#pragma unroll
    for (int i = 0; i < 4; ++i)
      a[i] = load8(&As[(size_t)(mh + i * 16 + l15) * 32 + quad * 8]);
#pragma unroll
    for (int j = 0; j < 4; ++j)
      bfr[j] = load8(&Bs[(size_t)(nh + j * 16 + l15) * 32 + quad * 8]);
    if (isv) {
#pragma unroll
      for (int i = 0; i < 4; ++i)
#pragma unroll
        for (int j = 0; j < 4; ++j) acc[i][j] = mfma16(a[i], bfr[j], acc[i][j]);
    } else {
#pragma unroll
      for (int i = 0; i < 4; ++i)
#pragma unroll
        for (int j = 0; j < 4; ++j) acc[i][j] = mfma16(bfr[j], a[i], acc[i][j]);
    }
  }

  if (isv) {
#pragma unroll
    for (int i = 0; i < 4; ++i)
#pragma unroll
      for (int j = 0; j < 4; ++j)
#pragma unroll
        for (int r = 0; r < 4; ++r) {
          int o = mbase + mh + i * 16 + quad * 4 + r;
          int nflat = nbase + nh + j * 16 + l15;
          int b = nflat >> 10, s = nflat & 1023;
          int oe = o - 1024; int n = oe >> 7, d = oe & 127;
          vout[(((size_t)b * 4 + n) * 128 + d) * 1024 + s] = (__bf16)acc[i][j][r];
        }
  } else {
    const bool isq = mbase < 512;
#pragma unroll
    for (int i = 0; i < 4; ++i)
#pragma unroll
      for (int j = 0; j < 4; ++j)
#pragma unroll
        for (int r = 0; r < 4; ++r) {
          int o = mbase + mh + i * 16 + l15;
          int nflat = nbase + nh + j * 16 + quad * 4 + r;
          int b = nflat >> 10, s = nflat & 1023;
          float val = acc[i][j][r];
          if (isq) {
            int n = o >> 7, d = o & 127;
            qout[(((size_t)b * 4 + n) * 1024 + s) * 128 + d] = (__bf16)(val * SCALE_Q);
          } else {
            int oe = o - 512; int n = oe >> 7, d = oe & 127;
            kout[(((size_t)b * 4 + n) * 1024 + s) * 128 + d] = (__bf16)val;
          }
        }
  }
}

// ------------------------------------------------------------------
// Flash attention v6: m97-staged K/V, per-wave 16 q-rows, c=0 softmax.
// PV computed as O^T = V * P^T (operand swap, same register contents) so
// the epilogue C-layout has lane = query s -> fully coalesced x read /
// x2 write (was 4KB-stride scatter: ~8.4M partial-line L2 transactions).
// lsum transposed lane->l15 via tiny LDS + one barrier.
// ------------------------------------------------------------------
__global__ __launch_bounds__(256, 2) void k_attn(
    const __bf16* __restrict__ q, const __bf16* __restrict__ kmat,
    const __bf16* __restrict__ vt, const __bf16* __restrict__ relh,
    const __bf16* __restrict__ relw, const float* __restrict__ x,
    float* __restrict__ x2) {
  __shared__ __bf16 Ks[4 * 64 * 32];    // 16 KB
  __shared__ __bf16 Vs[2 * 128 * 32];   // 16 KB
  __shared__ __bf16 P[4 * 16 * 68];     // 8.7 KB
  __shared__ __bf16 RWs[64][33];        // 4.2 KB
  __shared__ __bf16 RHs[64][33];        // 4.2 KB
  __shared__ float Lt[4][16];

  const int Lb = blockIdx.x;             // 0..511
  const int xcd = Lb & 7, local = Lb >> 3;
  const int bn = xcd * 4 + (local & 3);
  const int qblk = local >> 2;           // 0..15
  const int s0 = qblk * 64;

  const int t = threadIdx.x;
  const int wave = t >> 6, lane = t & 63;
  const int l15 = lane & 15, quad = lane >> 4;
  const size_t hoff = ((size_t)bn) << 17;
  const int s0w = s0 + wave * 16;
  const int wlo = (wave & 1) * 16;
  const int h0w = s0w >> 5;

  v8bf aq[4];
  {
    const __bf16* qp = q + hoff + (size_t)(s0w + l15) * 128;
#pragma unroll
    for (int kk = 0; kk < 4; ++kk) aq[kk] = load8(qp + kk * 32 + quad * 8);
  }

#pragma unroll
  for (int nt = 0; nt < 4; ++nt) {       // RWs via shift-write
    int rr = nt * 16 + l15;
    const __bf16* bp = relw + (size_t)rr * 128;
    f32x4 acc = {0.f, 0.f, 0.f, 0.f};
#pragma unroll
    for (int kk = 0; kk < 4; ++kk)
      acc = mfma16(aq[kk], load8(bp + kk * 32 + quad * 8), acc);
#pragma unroll
    for (int r = 0; r < 4; ++r) {
      int row = quad * 4 + r;
      int wj = rr + wlo + row - 31;
      if (wj >= 0 && wj < 32) RWs[wave * 16 + row][wj] = (__bf16)acc[r];
    }
  }
#pragma unroll
  for (int nt = 0; nt < 2; ++nt) {       // RHs direct
    int hj = nt * 16 + l15;
    const __bf16* bp = relh + (size_t)(hj - h0w + 31) * 128;
    f32x4 acc = {0.f, 0.f, 0.f, 0.f};
#pragma unroll
    for (int kk = 0; kk < 4; ++kk)
      acc = mfma16(aq[kk], load8(bp + kk * 32 + quad * 8), acc);
#pragma unroll
    for (int r = 0; r < 4; ++r) RHs[wave * 16 + quad * 4 + r][hj] = (__bf16)acc[r];
  }

  const int row0 = t >> 2, part8 = (t & 3) * 8;
  const __bf16* kg = kmat + hoff + (size_t)row0 * 128 + part8;
  const __bf16* vg = vt + hoff + (size_t)row0 * 1024 + part8;
  __bf16* ksw = Ks + wave * 512;
  __bf16* vsw = Vs + wave * 512;

  const f32x4 fz = {0.f, 0.f, 0.f, 0.f};
  float lsum[4] = {0.f, 0.f, 0.f, 0.f};
  f32x4 oacc[8];
#pragma unroll
  for (int dt = 0; dt < 8; ++dt) oacc[dt] = fz;
  __bf16* Pw = P + wave * 16 * 68;

#pragma unroll 1
  for (int iter = 0; iter < 16; ++iter) {
    const int j0 = iter * 64;
    __syncthreads();
#pragma unroll
    for (int kk = 0; kk < 4; ++kk)
      gld16(kg + (size_t)j0 * 128 + kk * 32, ksw + kk * 2048);
#pragma unroll
    for (int kk2 = 0; kk2 < 2; ++kk2)
#pragma unroll
      for (int dh = 0; dh < 2; ++dh)
        gld16(vg + (size_t)dh * 64 * 1024 + j0 + kk2 * 32,
              vsw + kk2 * 4096 + dh * 2048);
    __syncthreads();

    f32x4 sacc[4];
#pragma unroll
    for (int nj = 0; nj < 4; ++nj) {
      f32x4 a = fz;
#pragma unroll
      for (int kk = 0; kk < 4; ++kk)
        a = mfma16(aq[kk],
                   load8(&Ks[kk * 2048 + (nj * 16 + l15) * 32 + quad * 8]), a);
      sacc[nj] = a;
    }
    // bias (hoisted table loads) + exp(c=0) + partial l + stash P
    const int hjb = j0 >> 5;
#pragma unroll
    for (int r = 0; r < 4; ++r) {
      const int row = quad * 4 + r;
      const int gi = wave * 16 + row;
      const float rw0 = (float)RWs[gi][l15], rw1 = (float)RWs[gi][l15 + 16];
      const float rh0 = (float)RHs[gi][hjb], rh1 = (float)RHs[gi][hjb + 1];
#pragma unroll
      for (int nj = 0; nj < 4; ++nj) {
        float val = sacc[nj][r] + ((nj & 1) ? rw1 : rw0) + ((nj & 2) ? rh1 : rh0);
        float p = __expf(fminf(val, 60.0f));
        lsum[r] += p;
        Pw[row * 68 + nj * 16 + l15] = (__bf16)p;
      }
    }
    // PV as O^T = V * P^T: A = V^T tile (m=d), B = P (n=query) ->
    // D col = lane = query, row = d. Same register reads as before.
    v8bf pf[2];
#pragma unroll
    for (int kk2 = 0; kk2 < 2; ++kk2)
      pf[kk2] = *reinterpret_cast<const v8bf*>(&Pw[l15 * 68 + kk2 * 32 + quad * 8]);
#pragma unroll
    for (int dt = 0; dt < 8; ++dt) {
      f32x4 a = oacc[dt];
#pragma unroll
      for (int kk2 = 0; kk2 < 2; ++kk2)
        a = mfma16(load8(&Vs[kk2 * 4096 + (dt * 16 + l15) * 32 + quad * 8]),
                   pf[kk2], a);
      oacc[dt] = a;
    }
  }

  // reduce l across the 16-lane groups, then transpose lane->l15 via LDS
#pragma unroll
  for (int r = 0; r < 4; ++r)
#pragma unroll
    for (int msk = 8; msk >= 1; msk >>= 1) lsum[r] += __shfl_xor(lsum[r], msk);
  if (l15 == 0) {
#pragma unroll
    for (int r = 0; r < 4; ++r) Lt[wave][quad * 4 + r] = lsum[r];
  }
  __syncthreads();

  // epilogue: x2 = O/l + x ; lane = query s -> coalesced
  {
    const float linv = 1.0f / Lt[wave][l15];
    const int s = s0w + l15;
#pragma unroll
    for (int dt = 0; dt < 8; ++dt)
#pragma unroll
      for (int r = 0; r < 4; ++r) {
        int d = dt * 16 + quad * 4 + r;
        size_t idx = ((size_t)bn * 128 + d) * 1024 + s;
        x2[idx] = oacc[dt][r] * linv + x[idx];
      }
  }
}

// ------------------------------------------------------------------
// 3x3 conv, split-K=2 (unchanged): 512 blocks, 2/CU, XCD swizzle,
// BK=128, fp32 partials -> k_sum.
// ------------------------------------------------------------------
__global__ __launch_bounds__(256, 2) void k_conv(
    const __bf16* __restrict__ Wt, const __bf16* __restrict__ zp,
    float* __restrict__ part) {
  __shared__ __bf16 As[4 * 128 * 32];   // 32 KB
  __shared__ __bf16 Bs[4 * 128 * 32];   // 32 KB
  const int t = threadIdx.x;
  const int wave = t >> 6, lane = t & 63;
  const int l15 = lane & 15, quad = lane >> 4;

  const int id = blockIdx.x;            // 0..511
  const int combo = id & 7;
  const int ot = combo >> 1, sp = combo & 1;
  const int nt = id >> 3;
  const int mbase = ot * 128;
  const int nbase = nt * 128;
  const int cs = sp * 256;
  const int mh = (wave >> 1) * 64, nh = (wave & 1) * 64;

  const int row0 = t >> 2;
  const int part8 = (t & 3) * 8;
  const __bf16* gA0 = Wt + (size_t)(mbase + row0) * 512 + cs + part8;
  const __bf16* gA1 = gA0 + (size_t)64 * 512;
  const int n0 = nbase + row0;
  const int b0 = n0 >> 10, spn = n0 & 1023;
  const __bf16* gB0 =
      zp + ((size_t)(b0 * 34 + (spn >> 5) + 1) * 34 + (spn & 31) + 1) * 512 + cs + part8;
  const __bf16* gB1 = gB0 + (size_t)2 * 34 * 512;
  const int wofs = wave * 512;

  const f32x4 fz = {0.f, 0.f, 0.f, 0.f};
  f32x4 acc[4][4];
#pragma unroll
  for (int i = 0; i < 4; ++i)
#pragma unroll
    for (int j = 0; j < 4; ++j) acc[i][j] = fz;

#pragma unroll 1
  for (int tap = 0; tap < 9; ++tap) {
    const int dh = tap / 3 - 1, dw = tap % 3 - 1;
    const size_t aoff = (size_t)tap * 512 * 512;
    const int boff = (dh * 34 + dw) * 512;
#pragma unroll 1
    for (int k0 = 0; k0 < 256; k0 += 128) {
      __syncthreads();
#pragma unroll
      for (int c = 0; c < 4; ++c) {
        const int kq = k0 + c * 32;
        gld16(gA0 + aoff + kq, As + c * 4096 + wofs);
        gld16(gA1 + aoff + kq, As + c * 4096 + 2048 + wofs);
        gld16(gB0 + boff + kq, Bs + c * 4096 + wofs);
        gld16(gB1 + boff + kq, Bs + c * 4096 + 2048 + wofs);
      }
      __syncthreads();
#pragma unroll
      for (int c = 0; c < 4; ++c) {
        v8bf a[4], bfr[4];
#pragma unroll
        for (int i = 0; i < 4; ++i)
          a[i] = load8(&As[c * 4096 + (mh + i * 16 + l15) * 32 + quad * 8]);
#pragma unroll
        for (int j = 0; j < 4; ++j)
          bfr[j] = load8(&Bs[c * 4096 + (nh + j * 16 + l15) * 32 + quad * 8]);
#pragma unroll
        for (int i = 0; i < 4; ++i)
#pragma unroll
          for (int j = 0; j < 4; ++j) acc[i][j] = mfma16(a[i], bfr[j], acc[i][j]);
      }
    }
  }

  float* pout = part + (size_t)sp * 8 * 512 * 1024;
#pragma unroll
  for (int i = 0; i < 4; ++i)
#pragma unroll
    for (int j = 0; j < 4; ++j)
#pragma unroll
      for (int r = 0; r < 4; ++r) {
        int o = mbase + mh + i * 16 + quad * 4 + r;
        int nn = nbase + nh + j * 16 + l15;
        int bb2 = nn >> 10, s = nn & 1023;
        pout[((size_t)bb2 * 512 + o) * 1024 + s] = acc[i][j][r];
      }
}

// ------------------------------------------------------------------
// out = part0 + part1 + bias + x2   (f32x4 vectorized)
// ------------------------------------------------------------------
__global__ void k_sum(const float* __restrict__ part, const float* __restrict__ bias,
                      const float* __restrict__ x2, float* __restrict__ out) {
  int i = blockIdx.x * 256 + threadIdx.x;
  int o = (i >> 8) & 511;
  f32x4 p0 = reinterpret_cast<const f32x4*>(part)[i];
  f32x4 p1 = reinterpret_cast<const f32x4*>(part + (size_t)8 * 512 * 1024)[i];
  f32x4 xr = reinterpret_cast<const f32x4*>(x2)[i];
  float bo = bias[o];
  f32x4 r;
#pragma unroll
  for (int c = 0; c < 4; ++c) r[c] = p0[c] + p1[c] + bo + xr[c];
  reinterpret_cast<f32x4*>(out)[i] = r;
}

// ------------------------------------------------------------------
extern "C" void kernel_launch(void* const* d_in, const int* in_sizes, int n_in,
                              void* d_out, int out_size, void* d_ws, size_t ws_size,
                              hipStream_t stream) {
  const float* x    = (const float*)d_in[0];
  const float* wqk  = (const float*)d_in[1];
  const float* wv   = (const float*)d_in[2];
  const float* relh = (const float*)d_in[3];
  const float* relw = (const float*)d_in[4];
  const float* g1   = (const float*)d_in[5];
  const float* b1   = (const float*)d_in[6];
  const float* m1   = (const float*)d_in[7];
  const float* v1   = (const float*)d_in[8];
  const float* g2   = (const float*)d_in[9];
  const float* b2   = (const float*)d_in[10];
  const float* m2   = (const float*)d_in[11];
  const float* v2   = (const float*)d_in[12];
  const float* wfc  = (const float*)d_in[13];
  const float* bfc  = (const float*)d_in[14];
  float* out = (float*)d_out;

  char* p = (char*)d_ws;
  __bf16* y    = (__bf16*)p; p += (size_t)8 * 1024 * 512 * 2;       // (b,s,c)
  __bf16* qb   = (__bf16*)p; p += (size_t)8 * 4 * 1024 * 128 * 2;   // (b,n,s,d)
  __bf16* kb   = (__bf16*)p; p += (size_t)8 * 4 * 1024 * 128 * 2;   // (b,n,s,d)
  __bf16* vb   = (__bf16*)p; p += (size_t)8 * 4 * 1024 * 128 * 2;   // (b,n,d,s)
  __bf16* Wt   = (__bf16*)p; p += (size_t)9 * 512 * 512 * 2;        // (tap,o,c)
  __bf16* wqkb = (__bf16*)p; p += (size_t)1024 * 512 * 2;           // wall rows 0..1023
  __bf16* wvb  = (__bf16*)p; p += (size_t)512 * 512 * 2;            // wall rows 1024..1535
  __bf16* rhb  = (__bf16*)p; p += 32768;
  __bf16* rwb  = (__bf16*)p; p += 32768;
  float*  x2   = (float*)p;  p += (size_t)8 * 512 * 1024 * 4;       // (b,c,s) fp32
  __bf16* zpad = (__bf16*)p; p += (size_t)8 * 34 * 34 * 512 * 2;    // padded z
  // fp32 conv partials (2 x 16.78 MB) alias y+qb+kb+vb (dead after k_attn)
  float* part = (float*)d_ws;

  k_prep<<<dim3(6472), dim3(256), 0, stream>>>(wqk, wv, relh, relw, wfc,
                                               wqkb, wvb, rhb, rwb, Wt, (float*)zpad);
  k_bn1<<<dim3(32, 16, 8), dim3(32, 8), 0, stream>>>(x, g1, b1, m1, v1, y);
  k_proj<<<dim3(12, 64), dim3(256), 0, stream>>>(wqkb, y, qb, kb, vb);
  k_attn<<<dim3(512), dim3(256), 0, stream>>>(qb, kb, vb, rhb, rwb, x, x2);
  k_bn2<<<dim3(32, 16, 8), dim3(32, 8), 0, stream>>>(x2, g2, b2, m2, v2, zpad);
  k_conv<<<dim3(512), dim3(256), 0, stream>>>(Wt, zpad, part);
  k_sum<<<dim3(4096), dim3(256), 0, stream>>>(part, bfc, x2, out);
}